// Round 2
// baseline (991.420 us; speedup 1.0000x reference)
//
#include <hip/hip_runtime.h>
#include <math.h>

#define Bn 32
#define Mn 2048
#define Nn 65536      // Bn * Mn
#define Hn 32768      // Nn / 2 (chunk for race-free c0)
#define SDn 16
#define CWn 512
#define EPSf 1e-5f
#define KGF 8
#define WTOT 573440   // logical weight elements
#define LSC 2048.0f   // lo-plane scale (2^11)
#define LSCI (1.0f / 2048.0f)

typedef unsigned short u16;
typedef _Float16 fp16_t;
typedef __attribute__((ext_vector_type(8))) _Float16 h8v;  // MFMA A/B frag: 8 f16
typedef __attribute__((ext_vector_type(4))) float f4v;     // MFMA C/D frag: 4 fp32

__device__ __forceinline__ u16 f2h(float f) {
    union { fp16_t h; u16 u; } c; c.h = (fp16_t)f; return c.u;
}
__device__ __forceinline__ float h2f(u16 u) {
    union { fp16_t h; u16 u; } c; c.u = u; return (float)c.h;
}
__device__ __forceinline__ void fsplit(float f, u16& hi, u16& lo) {
    hi = f2h(f);
    lo = f2h((f - h2f(hi)) * LSC);
}
__device__ __forceinline__ float fjoin(u16 hi, u16 lo) {
    return h2f(hi) + h2f(lo) * LSCI;
}
// async global->LDS, 16 bytes/lane (dest must be wave-uniform base + lane*16)
__device__ __forceinline__ void gll16(const u16* g, u16* l) {
    __builtin_amdgcn_global_load_lds((const __attribute__((address_space(1))) void*)g,
                                     (__attribute__((address_space(3))) void*)l, 16, 0, 0);
}
// single-instruction f32 median-of-3 (sorted-list insertion primitive)
__device__ __forceinline__ float med3f(float a, float b, float c) {
#if __has_builtin(__builtin_amdgcn_fmed3f)
    return __builtin_amdgcn_fmed3f(a, b, c);
#else
    float r;
    asm("v_med3_f32 %0, %1, %2, %3" : "=v"(r) : "v"(a), "v"(b), "v"(c));
    return r;
#endif
}
// lexicographic comparator swap (rare exact fallback): keep (d0,i0) <= (d1,i1)
__device__ __forceinline__ void cswap(float& d0, int& i0, float& d1, int& i1) {
    const bool gt = (d0 > d1) || (d0 == d1 && i0 > i1);
    const float ta = gt ? d1 : d0, tb = gt ? d0 : d1;
    const int   ua = gt ? i1 : i0, ub = gt ? i0 : i1;
    d0 = ta; d1 = tb; i0 = ua; i1 = ub;
}

// ============================================================================
// prep: weights fp32 -> split layout, normalize s -> xs, zero stats (fused)
// ============================================================================
__global__ __launch_bounds__(256) void prep_kernel(
    const float* __restrict__ wm1, const float* __restrict__ wm2,
    const float* __restrict__ wc0, const float* __restrict__ wc1,
    const float* __restrict__ wc2, const float* __restrict__ wc3,
    const float* __restrict__ s,
    u16* __restrict__ wbuf, u16* __restrict__ xs, float* __restrict__ stats)
{
    const int bid = blockIdx.x;
    const int tid = threadIdx.x;
    if (bid < 2240) {
        // ---- weight conversion: [Cout][hi[Cin] | lo[Cin]] ----
        int i = bid * 256 + tid;
        float w; int r, k, Cin; size_t base;
        if (i < 8192) {                              // m1 padded [256][32]
            r = i >> 5; k = i & 31; Cin = 32; base = 0;
            w = (k < SDn) ? wm1[r * SDn + k] : 0.f;
        } else {
            int j = i - 8192;
            if (j < 131072)                    { r = j >> 8; k = j & 255; Cin = 256; base = 16384;   w = wm2[j]; }
            else if ((j -= 131072) < 262144)   { r = j >> 9; k = j & 511; Cin = 512; base = 278528;  w = wc0[j]; }
            else if ((j -= 262144) < 131072)   { r = j >> 9; k = j & 511; Cin = 512; base = 802816;  w = wc1[j]; }
            else if ((j -= 131072) < 32768)    { r = j >> 8; k = j & 255; Cin = 256; base = 1064960; w = wc2[j]; }
            else { j -= 32768;                   r = j >> 7; k = j & 127; Cin = 128; base = 1130496; w = wc3[j]; }
        }
        const size_t addr = base + (size_t)r * (2 * Cin) + k;
        u16 hi, lo; fsplit(w, hi, lo);
        wbuf[addr] = hi;
        wbuf[addr + Cin] = lo;
    } else if (bid < 2496) {
        // ---- normalize s[B,16,M] -> xs[N][64] (hi[32]|lo[32], upper 16 zero)
        const int b2 = bid - 2240;
        const int m = (b2 & 7) * 256 + tid;
        const int b = b2 >> 3;
        const float* sp = s + (size_t)b * SDn * Mn + m;
        float v[SDn]; float sq = 0.f;
#pragma unroll
        for (int c = 0; c < SDn; ++c) { v[c] = sp[(size_t)c * Mn]; sq += v[c] * v[c]; }
        const float r = 1.0f / sqrtf(sq);
        unsigned int uh[8], ul[8];
#pragma unroll
        for (int c = 0; c < 8; ++c) {
            u16 h0, l0, h1, l1;
            fsplit(v[2 * c] * r, h0, l0);
            fsplit(v[2 * c + 1] * r, h1, l1);
            uh[c] = (unsigned int)h0 | ((unsigned int)h1 << 16);
            ul[c] = (unsigned int)l0 | ((unsigned int)l1 << 16);
        }
        uint4* xp = (uint4*)(xs + (size_t)(b * Mn + m) * 64);
        xp[0] = make_uint4(uh[0], uh[1], uh[2], uh[3]);
        xp[1] = make_uint4(uh[4], uh[5], uh[6], uh[7]);
        xp[2] = make_uint4(0, 0, 0, 0);
        xp[3] = make_uint4(0, 0, 0, 0);
        xp[4] = make_uint4(ul[0], ul[1], ul[2], ul[3]);
        xp[5] = make_uint4(ul[4], ul[5], ul[6], ul[7]);
        xp[6] = make_uint4(0, 0, 0, 0);
        xp[7] = make_uint4(0, 0, 0, 0);
    } else {
        // ---- zero BN stats (4096 floats) ----
        float4 z4 = {0.f, 0.f, 0.f, 0.f};
        float4* sp4 = (float4*)stats;
#pragma unroll
        for (int k = 0; k < 4; ++k) sp4[tid * 4 + k] = z4;
    }
}

// ---- split fp16 MFMA GEMM, async staging, XCD remap, swizzled LDS ----------
// acc0 = Wh*Xh ; accL = Wh*Xl' + Wl'*Xh ; result = acc0 + accL/2048
// IBN=1: apply BN(scale,shift)+ReLU to B-frags between LDS read and MFMA
// (bit-identical to the former standalone bnrelu pass: same join/fma/max/split).
template<int RW, int CWv, int EPI, int MY, int IBN>
__global__ __launch_bounds__(256) void mfma_gemm(
    const u16* __restrict__ W, const u16* __restrict__ X, u16* __restrict__ Y,
    const float* __restrict__ bias, const float* __restrict__ zmod,
    const float* __restrict__ bnpin, float* __restrict__ stats, int Cout, int Cin)
{
    constexpr int BM = RW * 64, BN = CWv * 64;
    constexpr int ASEG = BM / 64, BSEG = BN / 64;
    constexpr int LMY = (MY == 1) ? 0 : (MY == 2) ? 1 : (MY == 4) ? 2 : 3;
    __shared__ __align__(16) u16 Ah[BM * 32], Al[BM * 32];
    __shared__ __align__(16) u16 Bh[BN * 32], Bl[BN * 32];
    __shared__ float sstat[(EPI == 2) ? (CWv * BM * 2) : 1];

    const int tid = threadIdx.x;
    const int wave = tid >> 6;
    const int lane = tid & 63;
    const int wm = wave & (RW - 1), wn = wave / RW;
    const int l15 = lane & 15, q = lane >> 4;
    const int lin = blockIdx.x;
    const int xcd = lin & 7;
    const int jj = lin >> 3;
    const int m0 = (jj & (MY - 1)) * BM;
    const int n0 = (xcd + ((jj >> LMY) << 3)) * BN;
    const int SW = 2 * Cin;

    f4v acc0[4][4], accL[4][4];
#pragma unroll
    for (int i = 0; i < 4; ++i)
#pragma unroll
        for (int j = 0; j < 4; ++j) {
            acc0[i][j] = (f4v){0.f, 0.f, 0.f, 0.f};
            accL[i][j] = (f4v){0.f, 0.f, 0.f, 0.f};
        }

    const int nsteps = Cin >> 5;
    for (int ks = 0; ks < nsteps; ++ks) {
        const int k0 = ks << 5;
        __syncthreads();   // previous iteration's frag reads done before overwrite
#pragma unroll
        for (int s = 0; s < ASEG; ++s) {
            const int flat = s * 256 + tid;
            const int row = flat >> 2;
            const int qs = (flat & 3) ^ ((row >> 1) & 3);   // swizzled source chunk
            const u16* ga = W + (size_t)(m0 + row) * SW + k0 + qs * 8;
            gll16(ga, Ah + flat * 8);
            gll16(ga + Cin, Al + flat * 8);
        }
#pragma unroll
        for (int s = 0; s < BSEG; ++s) {
            const int flat = s * 256 + tid;
            const int row = flat >> 2;
            const int qs = (flat & 3) ^ ((row >> 1) & 3);
            const u16* gb = X + (size_t)(n0 + row) * SW + k0 + qs * 8;
            gll16(gb, Bh + flat * 8);
            gll16(gb + Cin, Bl + flat * 8);
        }
        __syncthreads();   // drains vmcnt -> LDS tiles ready
        h8v afh[4], afl[4], bfh[4], bfl[4];
#pragma unroll
        for (int i = 0; i < 4; ++i) {
            const int ar = wm * 64 + i * 16 + l15;
            const int ao = ar * 32 + ((q ^ ((ar >> 1) & 3)) << 3);
            afh[i] = *(const h8v*)(Ah + ao);
            afl[i] = *(const h8v*)(Al + ao);
        }
#pragma unroll
        for (int j = 0; j < 4; ++j) {
            const int br = wn * 64 + j * 16 + l15;
            const int bo = br * 32 + ((q ^ ((br >> 1) & 3)) << 3);
            bfh[j] = *(const h8v*)(Bh + bo);
            bfl[j] = *(const h8v*)(Bl + bo);
        }
        if constexpr (IBN) {
            // frag elems are LOGICAL channels k0 + q*8 + e (read-side XOR
            // undoes the swizzle), uniform across l15 -> broadcast loads.
            const int kb = (k0 + q * 8) * 2;
            const float4 p0 = *(const float4*)(bnpin + kb);
            const float4 p1 = *(const float4*)(bnpin + kb + 4);
            const float4 p2 = *(const float4*)(bnpin + kb + 8);
            const float4 p3 = *(const float4*)(bnpin + kb + 12);
            const float sc8[8] = {p0.x, p0.z, p1.x, p1.z, p2.x, p2.z, p3.x, p3.z};
            const float sh8[8] = {p0.y, p0.w, p1.y, p1.w, p2.y, p2.w, p3.y, p3.w};
#pragma unroll
            for (int j = 0; j < 4; ++j) {
#pragma unroll
                for (int e = 0; e < 8; ++e) {
                    const float v = (float)bfh[j][e] + (float)bfl[j][e] * LSCI;
                    const float a = fmaxf(fmaf(v, sc8[e], sh8[e]), 0.f);
                    const fp16_t hh = (fp16_t)a;
                    bfh[j][e] = hh;
                    bfl[j][e] = (fp16_t)((a - (float)hh) * LSC);
                }
            }
        }
#pragma unroll
        for (int i = 0; i < 4; ++i)
#pragma unroll
            for (int j = 0; j < 4; ++j) {
                accL[i][j] = __builtin_amdgcn_mfma_f32_16x16x32_f16(afh[i], bfl[j], accL[i][j], 0, 0, 0);
                accL[i][j] = __builtin_amdgcn_mfma_f32_16x16x32_f16(afl[i], bfh[j], accL[i][j], 0, 0, 0);
                acc0[i][j] = __builtin_amdgcn_mfma_f32_16x16x32_f16(afh[i], bfh[j], acc0[i][j], 0, 0, 0);
            }
    }

    // ---- epilogue ----
    const int bb = n0 >> 11;
    const int SY = 2 * Cout;
#pragma unroll
    for (int i = 0; i < 4; ++i) {
        const int chb = m0 + wm * 64 + i * 16 + q * 4;
        const float4 bias4 = *(const float4*)(bias + chb);
        float z0 = 0.f, z1 = 0.f, z2 = 0.f, z3 = 0.f;
        if constexpr (EPI == 1) {
            const float4 z4 = *(const float4*)(zmod + bb * CWn + chb);
            z0 = z4.x; z1 = z4.y; z2 = z4.z; z3 = z4.w;
        }
        float ssum[4] = {0.f, 0.f, 0.f, 0.f}, ssq[4] = {0.f, 0.f, 0.f, 0.f};
#pragma unroll
        for (int j = 0; j < 4; ++j) {
            const int n = n0 + wn * 64 + j * 16 + l15;
            float v0 = fmaf(accL[i][j][0], LSCI, acc0[i][j][0]) + bias4.x;
            float v1 = fmaf(accL[i][j][1], LSCI, acc0[i][j][1]) + bias4.y;
            float v2 = fmaf(accL[i][j][2], LSCI, acc0[i][j][2]) + bias4.z;
            float v3 = fmaf(accL[i][j][3], LSCI, acc0[i][j][3]) + bias4.w;
            if constexpr (EPI == 0) {
                v0 = fmaxf(v0, 0.f); v1 = fmaxf(v1, 0.f); v2 = fmaxf(v2, 0.f); v3 = fmaxf(v3, 0.f);
            } else if constexpr (EPI == 1) {
                v0 = fminf(fmaxf(v0, -1.f), 1.f) * z0;
                v1 = fminf(fmaxf(v1, -1.f), 1.f) * z1;
                v2 = fminf(fmaxf(v2, -1.f), 1.f) * z2;
                v3 = fminf(fmaxf(v3, -1.f), 1.f) * z3;
            } else {
                ssum[0] += v0; ssum[1] += v1; ssum[2] += v2; ssum[3] += v3;
                ssq[0] += v0 * v0; ssq[1] += v1 * v1; ssq[2] += v2 * v2; ssq[3] += v3 * v3;
            }
            u16 h0, l0, h1, l1, h2, l2, h3, l3;
            fsplit(v0, h0, l0); fsplit(v1, h1, l1);
            fsplit(v2, h2, l2); fsplit(v3, h3, l3);
            ushort4 hv = {h0, h1, h2, h3};
            ushort4 lv = {l0, l1, l2, l3};
            u16* yp = Y + (size_t)n * SY + chb;
            *(ushort4*)yp = hv;
            *(ushort4*)(yp + Cout) = lv;
        }
        if constexpr (EPI == 2) {
#pragma unroll
            for (int r = 0; r < 4; ++r) {
#pragma unroll
                for (int d = 1; d < 16; d <<= 1) {
                    ssum[r] += __shfl_xor(ssum[r], d);
                    ssq[r]  += __shfl_xor(ssq[r], d);
                }
            }
            if (l15 == 0) {
                const int chl = wm * 64 + i * 16 + q * 4;
#pragma unroll
                for (int r = 0; r < 4; ++r) {
                    sstat[(wn * BM + chl + r) * 2]     = ssum[r];
                    sstat[(wn * BM + chl + r) * 2 + 1] = ssq[r];
                }
            }
        }
    }
    if constexpr (EPI == 2) {
        __syncthreads();
        if (tid < BM) {
            float s0 = 0.f, s1 = 0.f;
#pragma unroll
            for (int w = 0; w < CWv; ++w) {
                s0 += sstat[(w * BM + tid) * 2];
                s1 += sstat[(w * BM + tid) * 2 + 1];
            }
            atomicAdd(&stats[(m0 + tid) * 2], s0);
            atomicAdd(&stats[(m0 + tid) * 2 + 1], s1);
        }
    }
}

// ---- BN finalize: stats(sum,sumsq) -> (scale, shift) -----------------------
__global__ void finalize_kernel(const float* __restrict__ stats, const float* __restrict__ g,
                                const float* __restrict__ be, float* __restrict__ bnp, int C) {
    const int c = blockIdx.x * blockDim.x + threadIdx.x;
    if (c >= C) return;
    const float inv = 1.0f / (float)Nn;
    const float mean = stats[c * 2] * inv;
    const float var = stats[c * 2 + 1] * inv - mean * mean;
    const float sc = g[c] / sqrtf(var + EPSf);
    bnp[c * 2] = sc;
    bnp[c * 2 + 1] = fmaf(-mean, sc, be[c]);
}

// ---- final 64->3 conv (BN+ReLU on split input), vectorized loads -----------
__global__ __launch_bounds__(256) void finalconv_pm(
    const u16* __restrict__ y3, const float* __restrict__ bnp,
    const float* __restrict__ wout, const float* __restrict__ bout,
    float* __restrict__ pts)
{
    __shared__ float swo[3][64];
    __shared__ float ssc[64], ssh[64];
    const int tid = threadIdx.x;
    if (tid < 192) swo[tid / 64][tid % 64] = wout[tid];
    if (tid < 64) { ssc[tid] = bnp[tid * 2]; ssh[tid] = bnp[tid * 2 + 1]; }
    __syncthreads();
    const int n = blockIdx.x * 256 + tid;
    const uint4* yph = (const uint4*)(y3 + (size_t)n * 128);
    float d0 = bout[0], d1 = bout[1], d2 = bout[2];
#pragma unroll
    for (int cc = 0; cc < 8; ++cc) {
        const uint4 H = yph[cc];
        const uint4 L = yph[8 + cc];
        const unsigned hu[4] = {H.x, H.y, H.z, H.w};
        const unsigned lu[4] = {L.x, L.y, L.z, L.w};
#pragma unroll
        for (int e = 0; e < 4; ++e) {
            const int c = cc * 8 + e * 2;
            const float v0 = fjoin((u16)(hu[e] & 0xffff), (u16)(lu[e] & 0xffff));
            const float v1 = fjoin((u16)(hu[e] >> 16), (u16)(lu[e] >> 16));
            const float a0 = fmaxf(fmaf(v0, ssc[c], ssh[c]), 0.f);
            const float a1 = fmaxf(fmaf(v1, ssc[c + 1], ssh[c + 1]), 0.f);
            d0 = fmaf(a0, swo[0][c], d0); d0 = fmaf(a1, swo[0][c + 1], d0);
            d1 = fmaf(a0, swo[1][c], d1); d1 = fmaf(a1, swo[1][c + 1], d1);
            d2 = fmaf(a0, swo[2][c], d2); d2 = fmaf(a1, swo[2][c + 1], d2);
        }
    }
    float4 p = {d0, d1, d2, d0 * d0 + d1 * d1 + d2 * d2};
    *(float4*)(pts + (size_t)n * 4) = p;
}

// ---- graph filtering: med3 two-pass kNN with inline duplicate-tie fix ------
// Phase 1: per-thread top-9 KEYS (self included) via med3 sorted-insert:
//          bd[k] = med3(bd[k-1], bd[k], d) -- 9 independent ops/candidate.
// Merge:   3 shuffle rounds; rounds 1-2 re-sort via padded bitonic-16 clean;
//          round 3 only extracts T = 9th-smallest key (incl self), uniform.
// Phase 2: accumulate cnt/sum over d <= T (bit-identical fmaf), plus tie
//          stats at d == T: count, x-sum, min tie index.
// Epilogue: neigh_sum = sum_{d<=T} - surplus*q_tie - p, where surplus =
//          cnt - 9. Exact when all ties at T share coords (duplicate points
//          -- the empirically dominant tie source; round-0/round-1 identical
//          absmax confirms). x-moment check (sEQx == cntEQ*q_tie.x) verifies;
//          on fail -> exact lexicographic fallback (round-1's proven path).
__global__ __launch_bounds__(512) void knn_kernel(const float* __restrict__ pts,
                                                  float* __restrict__ out) {
    __shared__ __align__(16) float4 sp[Mn];   // 32 KB -> 4 blocks/CU (wave cap)
    const int b = blockIdx.y;
    const int tid = threadIdx.x;
    const float4* pb = (const float4*)pts + (size_t)b * Mn;
    for (int i = tid; i < Mn; i += 512) sp[i] = pb[i];
    __syncthreads();
    const int lane = tid & 63;
    const int wv = tid >> 6;                    // 0..7
    const int seg = lane & 7;                   // segment 0..7
    const int ptl = (wv << 3) | (lane >> 3);    // point-local 0..63
    const int m = blockIdx.x * 64 + ptl;
    const float4 p = sp[m];
    const int nb = seg << 8;

    // ---- phase 1: top-9 keys incl self, med3 sorted insertion ----
    float bd[9];
#pragma unroll
    for (int k = 0; k < 9; ++k) bd[k] = 1e30f;
    for (int t = 0; t < 256; ++t) {
        const int n = nb | ((t + seg) & 255);   // stagger start by seg (bank tiling)
        const float4 q = sp[n];
        const float dot = fmaf(p.x, q.x, fmaf(p.y, q.y, p.z * q.z));
        const float d = fmaf(-2.f, dot, q.w);   // key = dist - p.w (monotone)
        bd[8] = med3f(bd[7], bd[8], d);         // all read OLD neighbors ->
        bd[7] = med3f(bd[6], bd[7], d);         // descending in-place update ok
        bd[6] = med3f(bd[5], bd[6], d);
        bd[5] = med3f(bd[4], bd[5], d);
        bd[4] = med3f(bd[3], bd[4], d);
        bd[3] = med3f(bd[2], bd[3], d);
        bd[2] = med3f(bd[1], bd[2], d);
        bd[1] = med3f(bd[0], bd[1], d);
        bd[0] = fminf(bd[0], d);
    }
    // ---- merge across 8 segments ----
    // rounds 1,2: lowest-9 of two sorted-9 (bitonic min trick), then re-sort
    // via 7x(-inf)-padded bitonic-16 cleaner (input is up-down bitonic).
#pragma unroll
    for (int r = 1; r <= 2; r <<= 1) {
        float o[9];
#pragma unroll
        for (int k = 0; k < 9; ++k) o[k] = __shfl_xor(bd[k], r);
        float v[16];
#pragma unroll
        for (int k = 0; k < 7; ++k) v[k] = -1e38f;
#pragma unroll
        for (int k = 0; k < 9; ++k) v[7 + k] = fminf(bd[k], o[8 - k]);
#define CEV(i, j) { const float lo_ = fminf(v[i], v[j]); v[j] = fmaxf(v[i], v[j]); v[i] = lo_; }
        CEV(0,8); CEV(1,9); CEV(2,10); CEV(3,11); CEV(4,12); CEV(5,13); CEV(6,14); CEV(7,15);
        CEV(0,4); CEV(1,5); CEV(2,6); CEV(3,7); CEV(8,12); CEV(9,13); CEV(10,14); CEV(11,15);
        CEV(0,2); CEV(1,3); CEV(4,6); CEV(5,7); CEV(8,10); CEV(9,11); CEV(12,14); CEV(13,15);
        CEV(0,1); CEV(2,3); CEV(4,5); CEV(6,7); CEV(8,9); CEV(10,11); CEV(12,13); CEV(14,15);
#undef CEV
#pragma unroll
        for (int k = 0; k < 9; ++k) bd[k] = v[7 + k];
    }
    // round 3: only the max of the merged lowest-9 is needed (threshold T)
    float T;
    {
        float o[9];
#pragma unroll
        for (int k = 0; k < 9; ++k) o[k] = __shfl_xor(bd[k], 4);
        T = fminf(bd[0], o[8]);
#pragma unroll
        for (int k = 1; k < 9; ++k) T = fmaxf(T, fminf(bd[k], o[8 - k]));
    }

    // ---- phase 2: predicate accumulation + inline tie stats ----
    float cnt = 0.f, sx = 0.f, sy = 0.f, sz = 0.f;
    float cq = 0.f, ex = 0.f;
    unsigned tie = 0x7fffffffu;
    for (int t = 0; t < 256; ++t) {
        const int n = nb | ((t + seg) & 255);
        const float4 q = sp[n];
        const float dot = fmaf(p.x, q.x, fmaf(p.y, q.y, p.z * q.z));
        const float d = fmaf(-2.f, dot, q.w);   // bit-identical to phase 1
        const float sle = (d <= T) ? 1.f : 0.f;
        cnt += sle;
        sx = fmaf(sle, q.x, sx);
        sy = fmaf(sle, q.y, sy);
        sz = fmaf(sle, q.z, sz);
        const bool eq = (d == T);
        const float se = eq ? 1.f : 0.f;
        cq += se;
        ex = fmaf(se, q.x, ex);
        tie = min(tie, eq ? (unsigned)n : 0x7fffffffu);
    }
#pragma unroll
    for (int r = 1; r <= 4; r <<= 1) {
        cnt += __shfl_xor(cnt, r);
        sx  += __shfl_xor(sx, r);
        sy  += __shfl_xor(sy, r);
        sz  += __shfl_xor(sz, r);
        cq  += __shfl_xor(cq, r);
        ex  += __shfl_xor(ex, r);
        tie  = min(tie, (unsigned)__shfl_xor((int)tie, r));
    }

    const float surplus = cnt - 9.f;            // >= 0 by construction
    float qtx = 0.f, qty = 0.f, qtz = 0.f;
    bool bad = false;
    if (surplus > 0.5f) {                       // uniform per 8-lane group
        const float4 qt = sp[tie];
        qtx = qt.x; qty = qt.y; qtz = qt.z;
        // duplicate-verify: all ties at T must share q.x (x-moment check)
        bad = fabsf(ex - cq * qt.x) > fmaf(1e-4f, fabsf(ex), 1e-6f);
    }
    float* ob = out + (size_t)b * 3 * Mn;
    if (!bad) {
        if (seg == 0) {
            const float nx = sx - fmaf(surplus, qtx, p.x);
            const float ny = sy - fmaf(surplus, qty, p.y);
            const float nz = sz - fmaf(surplus, qtz, p.z);
            const float s8 = 0.125f;
            ob[m]          = 2.f * p.x - nx * s8;
            ob[Mn + m]     = 2.f * p.y - ny * s8;
            ob[2 * Mn + m] = 2.f * p.z - nz * s8;
        }
    } else {
        // ---- rare exact path: distinct-coord fp32 key tie at the boundary --
        // Full lexicographic (d, idx) selection, stable by index (= reference
        // jax.lax.top_k semantics under our computed keys). Group-uniform
        // branch: all shuffle partners (r<=4, same 8-lane group) are active.
        const int t_self = ((m >> 8) == seg) ? (((m & 255) - seg) & 255) : 300;
        float ed[8]; int ei[8];
#pragma unroll
        for (int k = 0; k < 8; ++k) { ed[k] = 1e30f; ei[k] = 0x7fffffff; }
        for (int t = 0; t < 256; ++t) {
            const int n = nb | ((t + seg) & 255);
            const float4 q = sp[n];
            const float dot = fmaf(p.x, q.x, fmaf(p.y, q.y, p.z * q.z));
            float d = fmaf(-2.f, dot, q.w);
            d = (t == t_self) ? 1e30f : d;
            const bool ins = (d < ed[7]) || (d == ed[7] && n < ei[7]);
            ed[7] = ins ? d : ed[7];
            ei[7] = ins ? n : ei[7];
            cswap(ed[6], ei[6], ed[7], ei[7]);
            cswap(ed[5], ei[5], ed[6], ei[6]);
            cswap(ed[4], ei[4], ed[5], ei[5]);
            cswap(ed[3], ei[3], ed[4], ei[4]);
            cswap(ed[2], ei[2], ed[3], ei[3]);
            cswap(ed[1], ei[1], ed[2], ei[2]);
            cswap(ed[0], ei[0], ed[1], ei[1]);
        }
#pragma unroll
        for (int r = 1; r <= 4; r <<= 1) {
            float od[8]; int oi[8];
#pragma unroll
            for (int k = 0; k < 8; ++k) {
                od[k] = __shfl_xor(ed[k], r);
                oi[k] = __shfl_xor(ei[k], r);
            }
            float md[8]; int mi[8];
#pragma unroll
            for (int k = 0; k < 8; ++k) {       // lowest-8 of union (bitonic, lex)
                const float da = ed[k], db = od[7 - k];
                const int   ia = ei[k], ib = oi[7 - k];
                const bool bl = (db < da) || (db == da && ib < ia);
                md[k] = bl ? db : da; mi[k] = bl ? ib : ia;
            }
#define CSM(a, c) cswap(md[a], mi[a], md[c], mi[c])
            CSM(0,4); CSM(1,5); CSM(2,6); CSM(3,7);
            CSM(0,2); CSM(1,3); CSM(4,6); CSM(5,7);
            CSM(0,1); CSM(2,3); CSM(4,5); CSM(6,7);
#undef CSM
#pragma unroll
            for (int k = 0; k < 8; ++k) { ed[k] = md[k]; ei[k] = mi[k]; }
        }
        if (seg == 0) {
            float nx = 0.f, ny = 0.f, nz = 0.f;
#pragma unroll
            for (int k = 0; k < 8; ++k) {
                const float4 q = sp[ei[k]];
                nx += q.x; ny += q.y; nz += q.z;
            }
            const float s8 = 0.125f;
            ob[m]          = 2.f * p.x - nx * s8;
            ob[Mn + m]     = 2.f * p.y - ny * s8;
            ob[2 * Mn + m] = 2.f * p.z - nz * s8;
        }
    }
}

// ============================================================================
extern "C" void kernel_launch(void* const* d_in, const int* in_sizes, int n_in,
                              void* d_out, int out_size, void* d_ws, size_t ws_size,
                              hipStream_t stream)
{
    (void)in_sizes; (void)n_in; (void)out_size;
    const float* z     = (const float*)d_in[0];
    const float* s     = (const float*)d_in[1];
    const float* w_m1  = (const float*)d_in[2];
    const float* b_m1  = (const float*)d_in[3];
    const float* w_m2  = (const float*)d_in[4];
    const float* b_m2  = (const float*)d_in[5];
    const float* w_out = (const float*)d_in[6];
    const float* b_out = (const float*)d_in[7];
    const float* w_c[4]  = {(const float*)d_in[8],  (const float*)d_in[12], (const float*)d_in[16], (const float*)d_in[20]};
    const float* b_c[4]  = {(const float*)d_in[9],  (const float*)d_in[13], (const float*)d_in[17], (const float*)d_in[21]};
    const float* g_c[4]  = {(const float*)d_in[10], (const float*)d_in[14], (const float*)d_in[18], (const float*)d_in[22]};
    const float* be_c[4] = {(const float*)d_in[11], (const float*)d_in[15], (const float*)d_in[19], (const float*)d_in[23]};

    char* ws = (char*)d_ws;
    const size_t MB = 1024ull * 1024ull;
    float* outp = (float*)d_out;
    if (ws_size < 208 * MB) return;   // proven: harness provides >= 208 MiB

    // -------- split-fp16 MFMA path (peak 204 MiB) --------
    u16*   wbuf  = (u16*)ws;
    float* stats = (float*)(ws + 3 * MB);
    float* bnp   = stats + 4096;
    u16*   xs  = (u16*)(ws + 4 * MB);
    u16*   x1  = (u16*)(ws + 12 * MB);
    u16*   x2  = (u16*)(ws + 76 * MB);
    u16*   y0  = (u16*)(ws + 12 * MB);   // contiguous after both chunks (RAW)
    u16*   y0a = (u16*)(ws + 12 * MB);   // rows [0, 32K)
    u16*   y0b = (u16*)(ws + 76 * MB);   // rows [32K, 64K)
    u16*   y1  = (u16*)(ws + 140 * MB);  // RAW c1 output
    u16*   y2  = (u16*)(ws + 12 * MB);   // RAW c2 output
    u16*   y3  = (u16*)(ws + 76 * MB);   // RAW c3 output
    float* pts = (float*)(ws + 4 * MB);

    prep_kernel<<<2497, 256, 0, stream>>>(w_m1, w_m2, w_c[0], w_c[1], w_c[2], w_c[3], s, wbuf, xs, stats);
    // m1: [N][32] -> [N][256]  (Ntiles=512, MY=2 -> 1024 blocks)
    mfma_gemm<2, 2, 0, 2, 0><<<1024, 256, 0, stream>>>(wbuf, xs, x1, b_m1, nullptr, nullptr, nullptr, 256, 32);
    // m2: [N][256] -> [N][512] (Ntiles=512, MY=4 -> 2048 blocks)
    mfma_gemm<2, 2, 1, 4, 0><<<2048, 256, 0, stream>>>(wbuf + 16384, x1, x2, b_m2, z, nullptr, nullptr, 512, 256);
    // c0 a/b: rows halves      (Ntiles=256, MY=4 -> 1024 blocks each) -> RAW y0 + stats
    mfma_gemm<2, 2, 2, 4, 0><<<1024, 256, 0, stream>>>(wbuf + 278528, x2, y0a, b_c[0], nullptr, nullptr, stats + 0, 512, 512);
    mfma_gemm<2, 2, 2, 4, 0><<<1024, 256, 0, stream>>>(wbuf + 278528, x2 + (size_t)Hn * 1024, y0b, b_c[0], nullptr, nullptr, stats + 0, 512, 512);
    finalize_kernel<<<2, 256, 0, stream>>>(stats + 0, g_c[0], be_c[0], bnp + 0, 512);
    // c1: BN0+ReLU fused on B-input (bnp+0); RAW y1 + stats
    mfma_gemm<2, 2, 2, 2, 1><<<1024, 256, 0, stream>>>(wbuf + 802816, y0, y1, b_c[1], nullptr, bnp + 0, stats + 1024, 256, 512);
    finalize_kernel<<<1, 256, 0, stream>>>(stats + 1024, g_c[1], be_c[1], bnp + 1024, 256);
    // c2: BN1+ReLU fused on B-input (bnp+1024); RAW y2 + stats
    mfma_gemm<2, 2, 2, 1, 1><<<512, 256, 0, stream>>>(wbuf + 1064960, y1, y2, b_c[2], nullptr, bnp + 1024, stats + 2048, 128, 256);
    finalize_kernel<<<1, 128, 0, stream>>>(stats + 2048, g_c[2], be_c[2], bnp + 2048, 128);
    // c3: BN2+ReLU fused on B-input (bnp+2048); RAW y3 + stats
    mfma_gemm<1, 4, 2, 1, 1><<<256, 256, 0, stream>>>(wbuf + 1130496, y2, y3, b_c[3], nullptr, bnp + 2048, stats + 3072, 64, 128);
    finalize_kernel<<<1, 64, 0, stream>>>(stats + 3072, g_c[3], be_c[3], bnp + 3072, 64);
    finalconv_pm<<<Nn / 256, 256, 0, stream>>>(y3, bnp + 3072, w_out, b_out, pts);
    knn_kernel<<<dim3(Mn / 64, Bn), 512, 0, stream>>>(pts, outp);
}

// Round 3
// 908.500 us; speedup vs baseline: 1.0913x; 1.0913x over previous
//
#include <hip/hip_runtime.h>
#include <math.h>

#define Bn 32
#define Mn 2048
#define Nn 65536      // Bn * Mn
#define Hn 32768      // Nn / 2 (chunk for race-free c0)
#define SDn 16
#define CWn 512
#define EPSf 1e-5f
#define KGF 8
#define WTOT 573440   // logical weight elements
#define LSC 2048.0f   // lo-plane scale (2^11)
#define LSCI (1.0f / 2048.0f)

typedef unsigned short u16;
typedef _Float16 fp16_t;
typedef __attribute__((ext_vector_type(8))) _Float16 h8v;  // MFMA A/B frag: 8 f16
typedef __attribute__((ext_vector_type(4))) float f4v;     // MFMA C/D frag: 4 fp32

__device__ __forceinline__ u16 f2h(float f) {
    union { fp16_t h; u16 u; } c; c.h = (fp16_t)f; return c.u;
}
__device__ __forceinline__ float h2f(u16 u) {
    union { fp16_t h; u16 u; } c; c.u = u; return (float)c.h;
}
__device__ __forceinline__ void fsplit(float f, u16& hi, u16& lo) {
    hi = f2h(f);
    lo = f2h((f - h2f(hi)) * LSC);
}
__device__ __forceinline__ float fjoin(u16 hi, u16 lo) {
    return h2f(hi) + h2f(lo) * LSCI;
}
// async global->LDS, 16 bytes/lane (dest must be wave-uniform base + lane*16)
__device__ __forceinline__ void gll16(const u16* g, u16* l) {
    __builtin_amdgcn_global_load_lds((const __attribute__((address_space(1))) void*)g,
                                     (__attribute__((address_space(3))) void*)l, 16, 0, 0);
}
// lexicographic comparator swap (merge tail): keep (d0,i0) <= (d1,i1)
__device__ __forceinline__ void cswap(float& d0, int& i0, float& d1, int& i1) {
    const bool gt = (d0 > d1) || (d0 == d1 && i0 > i1);
    const float ta = gt ? d1 : d0, tb = gt ? d0 : d1;
    const int   ua = gt ? i1 : i0, ub = gt ? i0 : i1;
    d0 = ta; d1 = tb; i0 = ua; i1 = ub;
}
// distance-only stable comparator swap (hot loop): swap iff d0 > d1 strictly
__device__ __forceinline__ void cswapd(float& d0, int& i0, float& d1, int& i1) {
    const bool gt = d0 > d1;
    const float ta = gt ? d1 : d0, tb = gt ? d0 : d1;
    const int   ua = gt ? i1 : i0, ub = gt ? i0 : i1;
    d0 = ta; d1 = tb; i0 = ua; i1 = ub;
}

// ============================================================================
// prep: weights fp32 -> split layout, normalize s -> xs, zero stats (fused)
// ============================================================================
__global__ __launch_bounds__(256) void prep_kernel(
    const float* __restrict__ wm1, const float* __restrict__ wm2,
    const float* __restrict__ wc0, const float* __restrict__ wc1,
    const float* __restrict__ wc2, const float* __restrict__ wc3,
    const float* __restrict__ s,
    u16* __restrict__ wbuf, u16* __restrict__ xs, float* __restrict__ stats)
{
    const int bid = blockIdx.x;
    const int tid = threadIdx.x;
    if (bid < 2240) {
        // ---- weight conversion: [Cout][hi[Cin] | lo[Cin]] ----
        int i = bid * 256 + tid;
        float w; int r, k, Cin; size_t base;
        if (i < 8192) {                              // m1 padded [256][32]
            r = i >> 5; k = i & 31; Cin = 32; base = 0;
            w = (k < SDn) ? wm1[r * SDn + k] : 0.f;
        } else {
            int j = i - 8192;
            if (j < 131072)                    { r = j >> 8; k = j & 255; Cin = 256; base = 16384;   w = wm2[j]; }
            else if ((j -= 131072) < 262144)   { r = j >> 9; k = j & 511; Cin = 512; base = 278528;  w = wc0[j]; }
            else if ((j -= 262144) < 131072)   { r = j >> 9; k = j & 511; Cin = 512; base = 802816;  w = wc1[j]; }
            else if ((j -= 131072) < 32768)    { r = j >> 8; k = j & 255; Cin = 256; base = 1064960; w = wc2[j]; }
            else { j -= 32768;                   r = j >> 7; k = j & 127; Cin = 128; base = 1130496; w = wc3[j]; }
        }
        const size_t addr = base + (size_t)r * (2 * Cin) + k;
        u16 hi, lo; fsplit(w, hi, lo);
        wbuf[addr] = hi;
        wbuf[addr + Cin] = lo;
    } else if (bid < 2496) {
        // ---- normalize s[B,16,M] -> xs[N][64] (hi[32]|lo[32], upper 16 zero)
        const int b2 = bid - 2240;
        const int m = (b2 & 7) * 256 + tid;
        const int b = b2 >> 3;
        const float* sp = s + (size_t)b * SDn * Mn + m;
        float v[SDn]; float sq = 0.f;
#pragma unroll
        for (int c = 0; c < SDn; ++c) { v[c] = sp[(size_t)c * Mn]; sq += v[c] * v[c]; }
        const float r = 1.0f / sqrtf(sq);
        unsigned int uh[8], ul[8];
#pragma unroll
        for (int c = 0; c < 8; ++c) {
            u16 h0, l0, h1, l1;
            fsplit(v[2 * c] * r, h0, l0);
            fsplit(v[2 * c + 1] * r, h1, l1);
            uh[c] = (unsigned int)h0 | ((unsigned int)h1 << 16);
            ul[c] = (unsigned int)l0 | ((unsigned int)l1 << 16);
        }
        uint4* xp = (uint4*)(xs + (size_t)(b * Mn + m) * 64);
        xp[0] = make_uint4(uh[0], uh[1], uh[2], uh[3]);
        xp[1] = make_uint4(uh[4], uh[5], uh[6], uh[7]);
        xp[2] = make_uint4(0, 0, 0, 0);
        xp[3] = make_uint4(0, 0, 0, 0);
        xp[4] = make_uint4(ul[0], ul[1], ul[2], ul[3]);
        xp[5] = make_uint4(ul[4], ul[5], ul[6], ul[7]);
        xp[6] = make_uint4(0, 0, 0, 0);
        xp[7] = make_uint4(0, 0, 0, 0);
    } else {
        // ---- zero BN stats (4096 floats) ----
        float4 z4 = {0.f, 0.f, 0.f, 0.f};
        float4* sp4 = (float4*)stats;
#pragma unroll
        for (int k = 0; k < 4; ++k) sp4[tid * 4 + k] = z4;
    }
}

// ---- split fp16 MFMA GEMM, async staging, XCD remap, swizzled LDS ----------
// acc0 = Wh*Xh ; accL = Wh*Xl' + Wl'*Xh ; result = acc0 + accL/2048
// IBN=1: BN(scale,shift)+ReLU fused on B-frags between LDS read and MFMA.
// BN finalize is folded into the prologue: each block derives (scale, shift)
// from the PRODUCER's stats/gamma/beta (bit-identical arithmetic to the old
// finalize_kernel) into a 4 KB LDS table -- removes 4 tiny drain launches.
template<int RW, int CWv, int EPI, int MY, int IBN>
__global__ __launch_bounds__(256) void mfma_gemm(
    const u16* __restrict__ W, const u16* __restrict__ X, u16* __restrict__ Y,
    const float* __restrict__ bias, const float* __restrict__ zmod,
    const float* __restrict__ bnst, const float* __restrict__ bng,
    const float* __restrict__ bnbe, float* __restrict__ stats, int Cout, int Cin)
{
    constexpr int BM = RW * 64, BN = CWv * 64;
    constexpr int ASEG = BM / 64, BSEG = BN / 64;
    constexpr int LMY = (MY == 1) ? 0 : (MY == 2) ? 1 : (MY == 4) ? 2 : 3;
    __shared__ __align__(16) u16 Ah[BM * 32], Al[BM * 32];
    __shared__ __align__(16) u16 Bh[BN * 32], Bl[BN * 32];
    __shared__ float sstat[(EPI == 2) ? (CWv * BM * 2) : 1];
    __shared__ __align__(16) float sbn[IBN ? 1024 : 4];   // (scale,shift) x Cin<=512

    const int tid = threadIdx.x;
    const int wave = tid >> 6;
    const int lane = tid & 63;
    const int wm = wave & (RW - 1), wn = wave / RW;
    const int l15 = lane & 15, q = lane >> 4;
    const int lin = blockIdx.x;
    const int xcd = lin & 7;
    const int jj = lin >> 3;
    const int m0 = (jj & (MY - 1)) * BM;
    const int n0 = (xcd + ((jj >> LMY) << 3)) * BN;
    const int SW = 2 * Cin;

    if constexpr (IBN) {
        const float inv = 1.0f / (float)Nn;
        for (int c = tid; c < Cin; c += 256) {
            const float mean = bnst[c * 2] * inv;
            const float var = bnst[c * 2 + 1] * inv - mean * mean;
            const float sc = bng[c] / sqrtf(var + EPSf);
            sbn[c * 2] = sc;
            sbn[c * 2 + 1] = fmaf(-mean, sc, bnbe[c]);
        }
        __syncthreads();
    }

    f4v acc0[4][4], accL[4][4];
#pragma unroll
    for (int i = 0; i < 4; ++i)
#pragma unroll
        for (int j = 0; j < 4; ++j) {
            acc0[i][j] = (f4v){0.f, 0.f, 0.f, 0.f};
            accL[i][j] = (f4v){0.f, 0.f, 0.f, 0.f};
        }

    const int nsteps = Cin >> 5;
    for (int ks = 0; ks < nsteps; ++ks) {
        const int k0 = ks << 5;
        __syncthreads();   // previous iteration's frag reads done before overwrite
#pragma unroll
        for (int s = 0; s < ASEG; ++s) {
            const int flat = s * 256 + tid;
            const int row = flat >> 2;
            const int qs = (flat & 3) ^ ((row >> 1) & 3);   // swizzled source chunk
            const u16* ga = W + (size_t)(m0 + row) * SW + k0 + qs * 8;
            gll16(ga, Ah + flat * 8);
            gll16(ga + Cin, Al + flat * 8);
        }
#pragma unroll
        for (int s = 0; s < BSEG; ++s) {
            const int flat = s * 256 + tid;
            const int row = flat >> 2;
            const int qs = (flat & 3) ^ ((row >> 1) & 3);
            const u16* gb = X + (size_t)(n0 + row) * SW + k0 + qs * 8;
            gll16(gb, Bh + flat * 8);
            gll16(gb + Cin, Bl + flat * 8);
        }
        __syncthreads();   // drains vmcnt -> LDS tiles ready
        h8v afh[4], afl[4], bfh[4], bfl[4];
#pragma unroll
        for (int i = 0; i < 4; ++i) {
            const int ar = wm * 64 + i * 16 + l15;
            const int ao = ar * 32 + ((q ^ ((ar >> 1) & 3)) << 3);
            afh[i] = *(const h8v*)(Ah + ao);
            afl[i] = *(const h8v*)(Al + ao);
        }
#pragma unroll
        for (int j = 0; j < 4; ++j) {
            const int br = wn * 64 + j * 16 + l15;
            const int bo = br * 32 + ((q ^ ((br >> 1) & 3)) << 3);
            bfh[j] = *(const h8v*)(Bh + bo);
            bfl[j] = *(const h8v*)(Bl + bo);
        }
        if constexpr (IBN) {
            // frag elems are LOGICAL channels k0 + q*8 + e (read-side XOR
            // undoes the swizzle), uniform across l15 -> broadcast LDS loads.
            const int kb = (k0 + q * 8) * 2;
            const float4 p0 = *(const float4*)(sbn + kb);
            const float4 p1 = *(const float4*)(sbn + kb + 4);
            const float4 p2 = *(const float4*)(sbn + kb + 8);
            const float4 p3 = *(const float4*)(sbn + kb + 12);
            const float sc8[8] = {p0.x, p0.z, p1.x, p1.z, p2.x, p2.z, p3.x, p3.z};
            const float sh8[8] = {p0.y, p0.w, p1.y, p1.w, p2.y, p2.w, p3.y, p3.w};
#pragma unroll
            for (int j = 0; j < 4; ++j) {
#pragma unroll
                for (int e = 0; e < 8; ++e) {
                    const float v = (float)bfh[j][e] + (float)bfl[j][e] * LSCI;
                    const float a = fmaxf(fmaf(v, sc8[e], sh8[e]), 0.f);
                    const fp16_t hh = (fp16_t)a;
                    bfh[j][e] = hh;
                    bfl[j][e] = (fp16_t)((a - (float)hh) * LSC);
                }
            }
        }
#pragma unroll
        for (int i = 0; i < 4; ++i)
#pragma unroll
            for (int j = 0; j < 4; ++j) {
                accL[i][j] = __builtin_amdgcn_mfma_f32_16x16x32_f16(afh[i], bfl[j], accL[i][j], 0, 0, 0);
                accL[i][j] = __builtin_amdgcn_mfma_f32_16x16x32_f16(afl[i], bfh[j], accL[i][j], 0, 0, 0);
                acc0[i][j] = __builtin_amdgcn_mfma_f32_16x16x32_f16(afh[i], bfh[j], acc0[i][j], 0, 0, 0);
            }
    }

    // ---- epilogue ----
    const int bb = n0 >> 11;
    const int SY = 2 * Cout;
#pragma unroll
    for (int i = 0; i < 4; ++i) {
        const int chb = m0 + wm * 64 + i * 16 + q * 4;
        const float4 bias4 = *(const float4*)(bias + chb);
        float z0 = 0.f, z1 = 0.f, z2 = 0.f, z3 = 0.f;
        if constexpr (EPI == 1) {
            const float4 z4 = *(const float4*)(zmod + bb * CWn + chb);
            z0 = z4.x; z1 = z4.y; z2 = z4.z; z3 = z4.w;
        }
        float ssum[4] = {0.f, 0.f, 0.f, 0.f}, ssq[4] = {0.f, 0.f, 0.f, 0.f};
#pragma unroll
        for (int j = 0; j < 4; ++j) {
            const int n = n0 + wn * 64 + j * 16 + l15;
            float v0 = fmaf(accL[i][j][0], LSCI, acc0[i][j][0]) + bias4.x;
            float v1 = fmaf(accL[i][j][1], LSCI, acc0[i][j][1]) + bias4.y;
            float v2 = fmaf(accL[i][j][2], LSCI, acc0[i][j][2]) + bias4.z;
            float v3 = fmaf(accL[i][j][3], LSCI, acc0[i][j][3]) + bias4.w;
            if constexpr (EPI == 0) {
                v0 = fmaxf(v0, 0.f); v1 = fmaxf(v1, 0.f); v2 = fmaxf(v2, 0.f); v3 = fmaxf(v3, 0.f);
            } else if constexpr (EPI == 1) {
                v0 = fminf(fmaxf(v0, -1.f), 1.f) * z0;
                v1 = fminf(fmaxf(v1, -1.f), 1.f) * z1;
                v2 = fminf(fmaxf(v2, -1.f), 1.f) * z2;
                v3 = fminf(fmaxf(v3, -1.f), 1.f) * z3;
            } else {
                ssum[0] += v0; ssum[1] += v1; ssum[2] += v2; ssum[3] += v3;
                ssq[0] += v0 * v0; ssq[1] += v1 * v1; ssq[2] += v2 * v2; ssq[3] += v3 * v3;
            }
            u16 h0, l0, h1, l1, h2, l2, h3, l3;
            fsplit(v0, h0, l0); fsplit(v1, h1, l1);
            fsplit(v2, h2, l2); fsplit(v3, h3, l3);
            ushort4 hv = {h0, h1, h2, h3};
            ushort4 lv = {l0, l1, l2, l3};
            u16* yp = Y + (size_t)n * SY + chb;
            *(ushort4*)yp = hv;
            *(ushort4*)(yp + Cout) = lv;
        }
        if constexpr (EPI == 2) {
#pragma unroll
            for (int r = 0; r < 4; ++r) {
#pragma unroll
                for (int d = 1; d < 16; d <<= 1) {
                    ssum[r] += __shfl_xor(ssum[r], d);
                    ssq[r]  += __shfl_xor(ssq[r], d);
                }
            }
            if (l15 == 0) {
                const int chl = wm * 64 + i * 16 + q * 4;
#pragma unroll
                for (int r = 0; r < 4; ++r) {
                    sstat[(wn * BM + chl + r) * 2]     = ssum[r];
                    sstat[(wn * BM + chl + r) * 2 + 1] = ssq[r];
                }
            }
        }
    }
    if constexpr (EPI == 2) {
        __syncthreads();
        if (tid < BM) {
            float s0 = 0.f, s1 = 0.f;
#pragma unroll
            for (int w = 0; w < CWv; ++w) {
                s0 += sstat[(w * BM + tid) * 2];
                s1 += sstat[(w * BM + tid) * 2 + 1];
            }
            atomicAdd(&stats[(m0 + tid) * 2], s0);
            atomicAdd(&stats[(m0 + tid) * 2 + 1], s1);
        }
    }
}

// ---- final 64->3 conv (BN finalize folded in; BN+ReLU on split input) ------
__global__ __launch_bounds__(256) void finalconv_pm(
    const u16* __restrict__ y3, const float* __restrict__ stats,
    const float* __restrict__ g, const float* __restrict__ be,
    const float* __restrict__ wout, const float* __restrict__ bout,
    float* __restrict__ pts)
{
    __shared__ float swo[3][64];
    __shared__ float ssc[64], ssh[64];
    const int tid = threadIdx.x;
    if (tid < 192) swo[tid / 64][tid % 64] = wout[tid];
    if (tid < 64) {
        const float inv = 1.0f / (float)Nn;
        const float mean = stats[tid * 2] * inv;
        const float var = stats[tid * 2 + 1] * inv - mean * mean;
        const float sc = g[tid] / sqrtf(var + EPSf);
        ssc[tid] = sc;
        ssh[tid] = fmaf(-mean, sc, be[tid]);
    }
    __syncthreads();
    const int n = blockIdx.x * 256 + tid;
    const uint4* yph = (const uint4*)(y3 + (size_t)n * 128);
    float d0 = bout[0], d1 = bout[1], d2 = bout[2];
#pragma unroll
    for (int cc = 0; cc < 8; ++cc) {
        const uint4 H = yph[cc];
        const uint4 L = yph[8 + cc];
        const unsigned hu[4] = {H.x, H.y, H.z, H.w};
        const unsigned lu[4] = {L.x, L.y, L.z, L.w};
#pragma unroll
        for (int e = 0; e < 4; ++e) {
            const int c = cc * 8 + e * 2;
            const float v0 = fjoin((u16)(hu[e] & 0xffff), (u16)(lu[e] & 0xffff));
            const float v1 = fjoin((u16)(hu[e] >> 16), (u16)(lu[e] >> 16));
            const float a0 = fmaxf(fmaf(v0, ssc[c], ssh[c]), 0.f);
            const float a1 = fmaxf(fmaf(v1, ssc[c + 1], ssh[c + 1]), 0.f);
            d0 = fmaf(a0, swo[0][c], d0); d0 = fmaf(a1, swo[0][c + 1], d0);
            d1 = fmaf(a0, swo[1][c], d1); d1 = fmaf(a1, swo[1][c + 1], d1);
            d2 = fmaf(a0, swo[2][c], d2); d2 = fmaf(a1, swo[2][c + 1], d2);
        }
    }
    float4 p = {d0, d1, d2, d0 * d0 + d1 * d1 + d2 * d2};
    *(float4*)(pts + (size_t)n * 4) = p;
}

// ---- graph filtering: 8 threads/point in one wave, branchless insert -------
// (round-0 exact one-pass kernel: proven 170 us, VALUBusy ~100%, no
//  divergence; robust to the abundant exact fp32 distance ties in this data)
__global__ __launch_bounds__(512) void knn_kernel(const float* __restrict__ pts,
                                                  float* __restrict__ out) {
    __shared__ __align__(16) float4 sp[Mn];   // 32 KB -> 4 blocks/CU (wave cap)
    const int b = blockIdx.y;
    const int tid = threadIdx.x;
    const float4* pb = (const float4*)pts + (size_t)b * Mn;
    for (int i = tid; i < Mn; i += 512) sp[i] = pb[i];
    __syncthreads();
    const int lane = tid & 63;
    const int wv = tid >> 6;                    // 0..7
    const int seg = lane & 7;                   // segment 0..7
    const int ptl = (wv << 3) | (lane >> 3);    // point-local 0..63
    const int m = blockIdx.x * 64 + ptl;
    const float4 p = sp[m];
    float bd[8]; int bi[8];
#pragma unroll
    for (int k = 0; k < 8; ++k) { bd[k] = 1e30f; bi[k] = 0x7fffffff; }
    const int nb = seg << 8;
    for (int t = 0; t < 256; ++t) {
        const int n = nb | ((t + seg) & 255);   // stagger start by seg (bank tiling)
        const float4 q = sp[n];
        const float dot = fmaf(p.x, q.x, fmaf(p.y, q.y, p.z * q.z));
        float d = fmaf(-2.f, dot, q.w);         // key = dist - p.w (monotone)
        d = (n == m) ? 1e30f : d;               // exclude self
        const bool ins = d < bd[7];
        bd[7] = ins ? d : bd[7];
        bi[7] = ins ? n : bi[7];
        cswapd(bd[6], bi[6], bd[7], bi[7]);
        cswapd(bd[5], bi[5], bd[6], bi[6]);
        cswapd(bd[4], bi[4], bd[5], bi[5]);
        cswapd(bd[3], bi[3], bd[4], bi[4]);
        cswapd(bd[2], bi[2], bd[3], bi[3]);
        cswapd(bd[1], bi[1], bd[2], bi[2]);
        cswapd(bd[0], bi[0], bd[1], bi[1]);
    }
    // 3 shuffle merge rounds: partner = lane ^ r (same point, r in {1,2,4})
#pragma unroll
    for (int r = 1; r <= 4; r <<= 1) {
        float od[8]; int oi[8];
#pragma unroll
        for (int k = 0; k < 8; ++k) {
            od[k] = __shfl_xor(bd[k], r);
            oi[k] = __shfl_xor(bi[k], r);
        }
        float md[8]; int mi[8];
#pragma unroll
        for (int k = 0; k < 8; ++k) {           // lowest-8 of union (bitonic)
            const float da = bd[k], db = od[7 - k];
            const int   ia = bi[k], ib = oi[7 - k];
            const bool bl = (db < da) || (db == da && ib < ia);
            md[k] = bl ? db : da; mi[k] = bl ? ib : ia;
        }
#define CSM(a, c) cswap(md[a], mi[a], md[c], mi[c])
        CSM(0,4); CSM(1,5); CSM(2,6); CSM(3,7);
        CSM(0,2); CSM(1,3); CSM(4,6); CSM(5,7);
        CSM(0,1); CSM(2,3); CSM(4,5); CSM(6,7);
#undef CSM
#pragma unroll
        for (int k = 0; k < 8; ++k) { bd[k] = md[k]; bi[k] = mi[k]; }
    }
    if (seg == 0) {
        float nx = 0.f, ny = 0.f, nz = 0.f;
#pragma unroll
        for (int k = 0; k < 8; ++k) { const float4 q = sp[bi[k]]; nx += q.x; ny += q.y; nz += q.z; }
        const float s8 = 0.125f;
        float* ob = out + (size_t)b * 3 * Mn;
        ob[m]          = 2.f * p.x - nx * s8;
        ob[Mn + m]     = 2.f * p.y - ny * s8;
        ob[2 * Mn + m] = 2.f * p.z - nz * s8;
    }
}

// ============================================================================
extern "C" void kernel_launch(void* const* d_in, const int* in_sizes, int n_in,
                              void* d_out, int out_size, void* d_ws, size_t ws_size,
                              hipStream_t stream)
{
    (void)in_sizes; (void)n_in; (void)out_size;
    const float* z     = (const float*)d_in[0];
    const float* s     = (const float*)d_in[1];
    const float* w_m1  = (const float*)d_in[2];
    const float* b_m1  = (const float*)d_in[3];
    const float* w_m2  = (const float*)d_in[4];
    const float* b_m2  = (const float*)d_in[5];
    const float* w_out = (const float*)d_in[6];
    const float* b_out = (const float*)d_in[7];
    const float* w_c[4]  = {(const float*)d_in[8],  (const float*)d_in[12], (const float*)d_in[16], (const float*)d_in[20]};
    const float* b_c[4]  = {(const float*)d_in[9],  (const float*)d_in[13], (const float*)d_in[17], (const float*)d_in[21]};
    const float* g_c[4]  = {(const float*)d_in[10], (const float*)d_in[14], (const float*)d_in[18], (const float*)d_in[22]};
    const float* be_c[4] = {(const float*)d_in[11], (const float*)d_in[15], (const float*)d_in[19], (const float*)d_in[23]};

    char* ws = (char*)d_ws;
    const size_t MB = 1024ull * 1024ull;
    float* outp = (float*)d_out;
    if (ws_size < 208 * MB) return;   // proven: harness provides >= 208 MiB

    // -------- split-fp16 MFMA path (peak 204 MiB) --------
    u16*   wbuf  = (u16*)ws;
    float* stats = (float*)(ws + 3 * MB);
    u16*   xs  = (u16*)(ws + 4 * MB);
    u16*   x1  = (u16*)(ws + 12 * MB);
    u16*   x2  = (u16*)(ws + 76 * MB);
    u16*   y0  = (u16*)(ws + 12 * MB);   // contiguous after both chunks (RAW)
    u16*   y0a = (u16*)(ws + 12 * MB);   // rows [0, 32K)
    u16*   y0b = (u16*)(ws + 76 * MB);   // rows [32K, 64K)
    u16*   y1  = (u16*)(ws + 140 * MB);  // RAW c1 output
    u16*   y2  = (u16*)(ws + 12 * MB);   // RAW c2 output
    u16*   y3  = (u16*)(ws + 76 * MB);   // RAW c3 output
    float* pts = (float*)(ws + 4 * MB);

    prep_kernel<<<2497, 256, 0, stream>>>(w_m1, w_m2, w_c[0], w_c[1], w_c[2], w_c[3], s, wbuf, xs, stats);
    // m1: [N][32] -> [N][256]  (Ntiles=512, MY=2 -> 1024 blocks)
    mfma_gemm<2, 2, 0, 2, 0><<<1024, 256, 0, stream>>>(wbuf, xs, x1, b_m1, nullptr, nullptr, nullptr, nullptr, nullptr, 256, 32);
    // m2: [N][256] -> [N][512] (Ntiles=512, MY=4 -> 2048 blocks)
    mfma_gemm<2, 2, 1, 4, 0><<<2048, 256, 0, stream>>>(wbuf + 16384, x1, x2, b_m2, z, nullptr, nullptr, nullptr, nullptr, 512, 256);
    // c0 a/b: rows halves      (Ntiles=256, MY=4 -> 1024 blocks each) -> RAW y0 + stats
    mfma_gemm<2, 2, 2, 4, 0><<<1024, 256, 0, stream>>>(wbuf + 278528, x2, y0a, b_c[0], nullptr, nullptr, nullptr, nullptr, stats + 0, 512, 512);
    mfma_gemm<2, 2, 2, 4, 0><<<1024, 256, 0, stream>>>(wbuf + 278528, x2 + (size_t)Hn * 1024, y0b, b_c[0], nullptr, nullptr, nullptr, nullptr, stats + 0, 512, 512);
    // c1: BN0+ReLU fused on B-input (finalize folded: stats+0, g0, be0); RAW y1 + stats
    mfma_gemm<2, 2, 2, 2, 1><<<1024, 256, 0, stream>>>(wbuf + 802816, y0, y1, b_c[1], nullptr, stats + 0, g_c[0], be_c[0], stats + 1024, 256, 512);
    // c2: BN1+ReLU fused on B-input (stats+1024, g1, be1); RAW y2 + stats
    mfma_gemm<2, 2, 2, 1, 1><<<512, 256, 0, stream>>>(wbuf + 1064960, y1, y2, b_c[2], nullptr, stats + 1024, g_c[1], be_c[1], stats + 2048, 128, 256);
    // c3: BN2+ReLU fused on B-input (stats+2048, g2, be2); RAW y3 + stats
    mfma_gemm<1, 4, 2, 1, 1><<<256, 256, 0, stream>>>(wbuf + 1130496, y2, y3, b_c[3], nullptr, stats + 2048, g_c[2], be_c[2], stats + 3072, 64, 128);
    // final conv: BN3 finalize folded (stats+3072, g3, be3)
    finalconv_pm<<<Nn / 256, 256, 0, stream>>>(y3, stats + 3072, g_c[3], be_c[3], w_out, b_out, pts);
    knn_kernel<<<dim3(Mn / 64, Bn), 512, 0, stream>>>(pts, outp);
}

// Round 4
// 876.696 us; speedup vs baseline: 1.1309x; 1.0363x over previous
//
#include <hip/hip_runtime.h>
#include <math.h>

#define Bn 32
#define Mn 2048
#define Nn 65536      // Bn * Mn
#define Hn 32768      // Nn / 2 (chunk for race-free c0)
#define SDn 16
#define CWn 512
#define EPSf 1e-5f
#define KGF 8
#define WTOT 573440   // logical weight elements
#define LSC 2048.0f   // lo-plane scale (2^11)
#define LSCI (1.0f / 2048.0f)

typedef unsigned short u16;
typedef _Float16 fp16_t;
typedef __attribute__((ext_vector_type(8))) _Float16 h8v;  // MFMA A/B frag: 8 f16
typedef __attribute__((ext_vector_type(4))) float f4v;     // MFMA C/D frag: 4 fp32

__device__ __forceinline__ u16 f2h(float f) {
    union { fp16_t h; u16 u; } c; c.h = (fp16_t)f; return c.u;
}
__device__ __forceinline__ float h2f(u16 u) {
    union { fp16_t h; u16 u; } c; c.u = u; return (float)c.h;
}
__device__ __forceinline__ void fsplit(float f, u16& hi, u16& lo) {
    hi = f2h(f);
    lo = f2h((f - h2f(hi)) * LSC);
}
__device__ __forceinline__ float fjoin(u16 hi, u16 lo) {
    return h2f(hi) + h2f(lo) * LSCI;
}
// async global->LDS, 16 bytes/lane (dest must be wave-uniform base + lane*16)
__device__ __forceinline__ void gll16(const u16* g, u16* l) {
    __builtin_amdgcn_global_load_lds((const __attribute__((address_space(1))) void*)g,
                                     (__attribute__((address_space(3))) void*)l, 16, 0, 0);
}
// lexicographic comparator swap (merge tail): keep (d0,i0) <= (d1,i1)
__device__ __forceinline__ void cswap(float& d0, int& i0, float& d1, int& i1) {
    const bool gt = (d0 > d1) || (d0 == d1 && i0 > i1);
    const float ta = gt ? d1 : d0, tb = gt ? d0 : d1;
    const int   ua = gt ? i1 : i0, ub = gt ? i0 : i1;
    d0 = ta; d1 = tb; i0 = ua; i1 = ub;
}
// distance-only stable comparator swap (hot loop): swap iff d0 > d1 strictly
__device__ __forceinline__ void cswapd(float& d0, int& i0, float& d1, int& i1) {
    const bool gt = d0 > d1;
    const float ta = gt ? d1 : d0, tb = gt ? d0 : d1;
    const int   ua = gt ? i1 : i0, ub = gt ? i0 : i1;
    d0 = ta; d1 = tb; i0 = ua; i1 = ub;
}

// ============================================================================
// prep: weights fp32 -> split layout, normalize s -> xs, zero stats (fused)
// ============================================================================
__global__ __launch_bounds__(256) void prep_kernel(
    const float* __restrict__ wm1, const float* __restrict__ wm2,
    const float* __restrict__ wc0, const float* __restrict__ wc1,
    const float* __restrict__ wc2, const float* __restrict__ wc3,
    const float* __restrict__ s,
    u16* __restrict__ wbuf, u16* __restrict__ xs, float* __restrict__ stats)
{
    const int bid = blockIdx.x;
    const int tid = threadIdx.x;
    if (bid < 2240) {
        // ---- weight conversion: [Cout][hi[Cin] | lo[Cin]] ----
        int i = bid * 256 + tid;
        float w; int r, k, Cin; size_t base;
        if (i < 8192) {                              // m1 padded [256][32]
            r = i >> 5; k = i & 31; Cin = 32; base = 0;
            w = (k < SDn) ? wm1[r * SDn + k] : 0.f;
        } else {
            int j = i - 8192;
            if (j < 131072)                    { r = j >> 8; k = j & 255; Cin = 256; base = 16384;   w = wm2[j]; }
            else if ((j -= 131072) < 262144)   { r = j >> 9; k = j & 511; Cin = 512; base = 278528;  w = wc0[j]; }
            else if ((j -= 262144) < 131072)   { r = j >> 9; k = j & 511; Cin = 512; base = 802816;  w = wc1[j]; }
            else if ((j -= 131072) < 32768)    { r = j >> 8; k = j & 255; Cin = 256; base = 1064960; w = wc2[j]; }
            else { j -= 32768;                   r = j >> 7; k = j & 127; Cin = 128; base = 1130496; w = wc3[j]; }
        }
        const size_t addr = base + (size_t)r * (2 * Cin) + k;
        u16 hi, lo; fsplit(w, hi, lo);
        wbuf[addr] = hi;
        wbuf[addr + Cin] = lo;
    } else if (bid < 2496) {
        // ---- normalize s[B,16,M] -> xs[N][64] (hi[32]|lo[32], upper 16 zero)
        const int b2 = bid - 2240;
        const int m = (b2 & 7) * 256 + tid;
        const int b = b2 >> 3;
        const float* sp = s + (size_t)b * SDn * Mn + m;
        float v[SDn]; float sq = 0.f;
#pragma unroll
        for (int c = 0; c < SDn; ++c) { v[c] = sp[(size_t)c * Mn]; sq += v[c] * v[c]; }
        const float r = 1.0f / sqrtf(sq);
        unsigned int uh[8], ul[8];
#pragma unroll
        for (int c = 0; c < 8; ++c) {
            u16 h0, l0, h1, l1;
            fsplit(v[2 * c] * r, h0, l0);
            fsplit(v[2 * c + 1] * r, h1, l1);
            uh[c] = (unsigned int)h0 | ((unsigned int)h1 << 16);
            ul[c] = (unsigned int)l0 | ((unsigned int)l1 << 16);
        }
        uint4* xp = (uint4*)(xs + (size_t)(b * Mn + m) * 64);
        xp[0] = make_uint4(uh[0], uh[1], uh[2], uh[3]);
        xp[1] = make_uint4(uh[4], uh[5], uh[6], uh[7]);
        xp[2] = make_uint4(0, 0, 0, 0);
        xp[3] = make_uint4(0, 0, 0, 0);
        xp[4] = make_uint4(ul[0], ul[1], ul[2], ul[3]);
        xp[5] = make_uint4(ul[4], ul[5], ul[6], ul[7]);
        xp[6] = make_uint4(0, 0, 0, 0);
        xp[7] = make_uint4(0, 0, 0, 0);
    } else {
        // ---- zero BN stats (4096 floats) ----
        float4 z4 = {0.f, 0.f, 0.f, 0.f};
        float4* sp4 = (float4*)stats;
#pragma unroll
        for (int k = 0; k < 4; ++k) sp4[tid * 4 + k] = z4;
    }
}

// ---- split fp16 MFMA GEMM, async staging, XCD remap, swizzled LDS ----------
// acc0 = Wh*Xh ; accL = Wh*Xl' + Wl'*Xh ; result = acc0 + accL/2048
// IBN=1: BN(scale,shift)+ReLU fused on B-frags between LDS read and MFMA.
// BN finalize is folded into the prologue: each block derives (scale, shift)
// from the PRODUCER's stats/gamma/beta (bit-identical arithmetic to the old
// finalize_kernel) into a 4 KB LDS table -- removes 4 tiny drain launches.
template<int RW, int CWv, int EPI, int MY, int IBN>
__global__ __launch_bounds__(256) void mfma_gemm(
    const u16* __restrict__ W, const u16* __restrict__ X, u16* __restrict__ Y,
    const float* __restrict__ bias, const float* __restrict__ zmod,
    const float* __restrict__ bnst, const float* __restrict__ bng,
    const float* __restrict__ bnbe, float* __restrict__ stats, int Cout, int Cin)
{
    constexpr int BM = RW * 64, BN = CWv * 64;
    constexpr int ASEG = BM / 64, BSEG = BN / 64;
    constexpr int LMY = (MY == 1) ? 0 : (MY == 2) ? 1 : (MY == 4) ? 2 : 3;
    __shared__ __align__(16) u16 Ah[BM * 32], Al[BM * 32];
    __shared__ __align__(16) u16 Bh[BN * 32], Bl[BN * 32];
    __shared__ float sstat[(EPI == 2) ? (CWv * BM * 2) : 1];
    __shared__ __align__(16) float sbn[IBN ? 1024 : 4];   // (scale,shift) x Cin<=512

    const int tid = threadIdx.x;
    const int wave = tid >> 6;
    const int lane = tid & 63;
    const int wm = wave & (RW - 1), wn = wave / RW;
    const int l15 = lane & 15, q = lane >> 4;
    const int lin = blockIdx.x;
    const int xcd = lin & 7;
    const int jj = lin >> 3;
    const int m0 = (jj & (MY - 1)) * BM;
    const int n0 = (xcd + ((jj >> LMY) << 3)) * BN;
    const int SW = 2 * Cin;

    if constexpr (IBN) {
        const float inv = 1.0f / (float)Nn;
        for (int c = tid; c < Cin; c += 256) {
            const float mean = bnst[c * 2] * inv;
            const float var = bnst[c * 2 + 1] * inv - mean * mean;
            const float sc = bng[c] / sqrtf(var + EPSf);
            sbn[c * 2] = sc;
            sbn[c * 2 + 1] = fmaf(-mean, sc, bnbe[c]);
        }
        __syncthreads();
    }

    f4v acc0[4][4], accL[4][4];
#pragma unroll
    for (int i = 0; i < 4; ++i)
#pragma unroll
        for (int j = 0; j < 4; ++j) {
            acc0[i][j] = (f4v){0.f, 0.f, 0.f, 0.f};
            accL[i][j] = (f4v){0.f, 0.f, 0.f, 0.f};
        }

    const int nsteps = Cin >> 5;
    for (int ks = 0; ks < nsteps; ++ks) {
        const int k0 = ks << 5;
        __syncthreads();   // previous iteration's frag reads done before overwrite
#pragma unroll
        for (int s = 0; s < ASEG; ++s) {
            const int flat = s * 256 + tid;
            const int row = flat >> 2;
            const int qs = (flat & 3) ^ ((row >> 1) & 3);   // swizzled source chunk
            const u16* ga = W + (size_t)(m0 + row) * SW + k0 + qs * 8;
            gll16(ga, Ah + flat * 8);
            gll16(ga + Cin, Al + flat * 8);
        }
#pragma unroll
        for (int s = 0; s < BSEG; ++s) {
            const int flat = s * 256 + tid;
            const int row = flat >> 2;
            const int qs = (flat & 3) ^ ((row >> 1) & 3);
            const u16* gb = X + (size_t)(n0 + row) * SW + k0 + qs * 8;
            gll16(gb, Bh + flat * 8);
            gll16(gb + Cin, Bl + flat * 8);
        }
        __syncthreads();   // drains vmcnt -> LDS tiles ready
        h8v afh[4], afl[4], bfh[4], bfl[4];
#pragma unroll
        for (int i = 0; i < 4; ++i) {
            const int ar = wm * 64 + i * 16 + l15;
            const int ao = ar * 32 + ((q ^ ((ar >> 1) & 3)) << 3);
            afh[i] = *(const h8v*)(Ah + ao);
            afl[i] = *(const h8v*)(Al + ao);
        }
#pragma unroll
        for (int j = 0; j < 4; ++j) {
            const int br = wn * 64 + j * 16 + l15;
            const int bo = br * 32 + ((q ^ ((br >> 1) & 3)) << 3);
            bfh[j] = *(const h8v*)(Bh + bo);
            bfl[j] = *(const h8v*)(Bl + bo);
        }
        if constexpr (IBN) {
            // frag elems are LOGICAL channels k0 + q*8 + e (read-side XOR
            // undoes the swizzle), uniform across l15 -> broadcast LDS loads.
            const int kb = (k0 + q * 8) * 2;
            const float4 p0 = *(const float4*)(sbn + kb);
            const float4 p1 = *(const float4*)(sbn + kb + 4);
            const float4 p2 = *(const float4*)(sbn + kb + 8);
            const float4 p3 = *(const float4*)(sbn + kb + 12);
            const float sc8[8] = {p0.x, p0.z, p1.x, p1.z, p2.x, p2.z, p3.x, p3.z};
            const float sh8[8] = {p0.y, p0.w, p1.y, p1.w, p2.y, p2.w, p3.y, p3.w};
#pragma unroll
            for (int j = 0; j < 4; ++j) {
#pragma unroll
                for (int e = 0; e < 8; ++e) {
                    const float v = (float)bfh[j][e] + (float)bfl[j][e] * LSCI;
                    const float a = fmaxf(fmaf(v, sc8[e], sh8[e]), 0.f);
                    const fp16_t hh = (fp16_t)a;
                    bfh[j][e] = hh;
                    bfl[j][e] = (fp16_t)((a - (float)hh) * LSC);
                }
            }
        }
#pragma unroll
        for (int i = 0; i < 4; ++i)
#pragma unroll
            for (int j = 0; j < 4; ++j) {
                accL[i][j] = __builtin_amdgcn_mfma_f32_16x16x32_f16(afh[i], bfl[j], accL[i][j], 0, 0, 0);
                accL[i][j] = __builtin_amdgcn_mfma_f32_16x16x32_f16(afl[i], bfh[j], accL[i][j], 0, 0, 0);
                acc0[i][j] = __builtin_amdgcn_mfma_f32_16x16x32_f16(afh[i], bfh[j], acc0[i][j], 0, 0, 0);
            }
    }

    // ---- epilogue ----
    const int bb = n0 >> 11;
    const int SY = 2 * Cout;
#pragma unroll
    for (int i = 0; i < 4; ++i) {
        const int chb = m0 + wm * 64 + i * 16 + q * 4;
        const float4 bias4 = *(const float4*)(bias + chb);
        float z0 = 0.f, z1 = 0.f, z2 = 0.f, z3 = 0.f;
        if constexpr (EPI == 1) {
            const float4 z4 = *(const float4*)(zmod + bb * CWn + chb);
            z0 = z4.x; z1 = z4.y; z2 = z4.z; z3 = z4.w;
        }
        float ssum[4] = {0.f, 0.f, 0.f, 0.f}, ssq[4] = {0.f, 0.f, 0.f, 0.f};
#pragma unroll
        for (int j = 0; j < 4; ++j) {
            const int n = n0 + wn * 64 + j * 16 + l15;
            float v0 = fmaf(accL[i][j][0], LSCI, acc0[i][j][0]) + bias4.x;
            float v1 = fmaf(accL[i][j][1], LSCI, acc0[i][j][1]) + bias4.y;
            float v2 = fmaf(accL[i][j][2], LSCI, acc0[i][j][2]) + bias4.z;
            float v3 = fmaf(accL[i][j][3], LSCI, acc0[i][j][3]) + bias4.w;
            if constexpr (EPI == 0) {
                v0 = fmaxf(v0, 0.f); v1 = fmaxf(v1, 0.f); v2 = fmaxf(v2, 0.f); v3 = fmaxf(v3, 0.f);
            } else if constexpr (EPI == 1) {
                v0 = fminf(fmaxf(v0, -1.f), 1.f) * z0;
                v1 = fminf(fmaxf(v1, -1.f), 1.f) * z1;
                v2 = fminf(fmaxf(v2, -1.f), 1.f) * z2;
                v3 = fminf(fmaxf(v3, -1.f), 1.f) * z3;
            } else {
                ssum[0] += v0; ssum[1] += v1; ssum[2] += v2; ssum[3] += v3;
                ssq[0] += v0 * v0; ssq[1] += v1 * v1; ssq[2] += v2 * v2; ssq[3] += v3 * v3;
            }
            u16 h0, l0, h1, l1, h2, l2, h3, l3;
            fsplit(v0, h0, l0); fsplit(v1, h1, l1);
            fsplit(v2, h2, l2); fsplit(v3, h3, l3);
            ushort4 hv = {h0, h1, h2, h3};
            ushort4 lv = {l0, l1, l2, l3};
            u16* yp = Y + (size_t)n * SY + chb;
            *(ushort4*)yp = hv;
            *(ushort4*)(yp + Cout) = lv;
        }
        if constexpr (EPI == 2) {
#pragma unroll
            for (int r = 0; r < 4; ++r) {
#pragma unroll
                for (int d = 1; d < 16; d <<= 1) {
                    ssum[r] += __shfl_xor(ssum[r], d);
                    ssq[r]  += __shfl_xor(ssq[r], d);
                }
            }
            if (l15 == 0) {
                const int chl = wm * 64 + i * 16 + q * 4;
#pragma unroll
                for (int r = 0; r < 4; ++r) {
                    sstat[(wn * BM + chl + r) * 2]     = ssum[r];
                    sstat[(wn * BM + chl + r) * 2 + 1] = ssq[r];
                }
            }
        }
    }
    if constexpr (EPI == 2) {
        __syncthreads();
        if (tid < BM) {
            float s0 = 0.f, s1 = 0.f;
#pragma unroll
            for (int w = 0; w < CWv; ++w) {
                s0 += sstat[(w * BM + tid) * 2];
                s1 += sstat[(w * BM + tid) * 2 + 1];
            }
            atomicAdd(&stats[(m0 + tid) * 2], s0);
            atomicAdd(&stats[(m0 + tid) * 2 + 1], s1);
        }
    }
}

// ---- final 64->3 conv (BN finalize folded in; BN+ReLU on split input) ------
__global__ __launch_bounds__(256) void finalconv_pm(
    const u16* __restrict__ y3, const float* __restrict__ stats,
    const float* __restrict__ g, const float* __restrict__ be,
    const float* __restrict__ wout, const float* __restrict__ bout,
    float* __restrict__ pts)
{
    __shared__ float swo[3][64];
    __shared__ float ssc[64], ssh[64];
    const int tid = threadIdx.x;
    if (tid < 192) swo[tid / 64][tid % 64] = wout[tid];
    if (tid < 64) {
        const float inv = 1.0f / (float)Nn;
        const float mean = stats[tid * 2] * inv;
        const float var = stats[tid * 2 + 1] * inv - mean * mean;
        const float sc = g[tid] / sqrtf(var + EPSf);
        ssc[tid] = sc;
        ssh[tid] = fmaf(-mean, sc, be[tid]);
    }
    __syncthreads();
    const int n = blockIdx.x * 256 + tid;
    const uint4* yph = (const uint4*)(y3 + (size_t)n * 128);
    float d0 = bout[0], d1 = bout[1], d2 = bout[2];
#pragma unroll
    for (int cc = 0; cc < 8; ++cc) {
        const uint4 H = yph[cc];
        const uint4 L = yph[8 + cc];
        const unsigned hu[4] = {H.x, H.y, H.z, H.w};
        const unsigned lu[4] = {L.x, L.y, L.z, L.w};
#pragma unroll
        for (int e = 0; e < 4; ++e) {
            const int c = cc * 8 + e * 2;
            const float v0 = fjoin((u16)(hu[e] & 0xffff), (u16)(lu[e] & 0xffff));
            const float v1 = fjoin((u16)(hu[e] >> 16), (u16)(lu[e] >> 16));
            const float a0 = fmaxf(fmaf(v0, ssc[c], ssh[c]), 0.f);
            const float a1 = fmaxf(fmaf(v1, ssc[c + 1], ssh[c + 1]), 0.f);
            d0 = fmaf(a0, swo[0][c], d0); d0 = fmaf(a1, swo[0][c + 1], d0);
            d1 = fmaf(a0, swo[1][c], d1); d1 = fmaf(a1, swo[1][c + 1], d1);
            d2 = fmaf(a0, swo[2][c], d2); d2 = fmaf(a1, swo[2][c + 1], d2);
        }
    }
    float4 p = {d0, d1, d2, d0 * d0 + d1 * d1 + d2 * d2};
    *(float4*)(pts + (size_t)n * 4) = p;
}

// ---- graph filtering: 8 threads/point, batch-4 sorting-network insert ------
// Exact top-8 by strict-d comparators (tie order within a thread differs
// from scan-order insert, but exact-key ties are coordinate duplicates --
// validated rounds 0/1: different tie-break rules, identical output).
// Per 4 candidates: sort-4 network (5 comparators) + bitonic lowest-8 merge
// (4 min-selects + 12-comparator cleaner) ~= 33 VALU inst/candidate vs ~48
// for the 7-deep per-candidate chain.
__global__ __launch_bounds__(512) void knn_kernel(const float* __restrict__ pts,
                                                  float* __restrict__ out) {
    __shared__ __align__(16) float4 sp[Mn];   // 32 KB -> 4 blocks/CU (wave cap)
    const int b = blockIdx.y;
    const int tid = threadIdx.x;
    const float4* pb = (const float4*)pts + (size_t)b * Mn;
    for (int i = tid; i < Mn; i += 512) sp[i] = pb[i];
    __syncthreads();
    const int lane = tid & 63;
    const int wv = tid >> 6;                    // 0..7
    const int seg = lane & 7;                   // segment 0..7
    const int ptl = (wv << 3) | (lane >> 3);    // point-local 0..63
    const int m = blockIdx.x * 64 + ptl;
    const float4 p = sp[m];
    float bd[8]; int bi[8];
#pragma unroll
    for (int k = 0; k < 8; ++k) { bd[k] = 1e30f; bi[k] = 0x7fffffff; }
    const int nb = seg << 8;
    for (int t = 0; t < 256; t += 4) {
        // ---- load 4 candidates, compute keys ----
        float cd[4]; int ci[4];
#pragma unroll
        for (int i = 0; i < 4; ++i) {
            const int n = nb | ((t + seg + i) & 255);   // stagger by seg (bank tiling)
            const float4 q = sp[n];
            const float dot = fmaf(p.x, q.x, fmaf(p.y, q.y, p.z * q.z));
            float d = fmaf(-2.f, dot, q.w);             // key = dist - p.w (monotone)
            d = (n == m) ? 1e30f : d;                   // exclude self
            cd[i] = d; ci[i] = n;
        }
        // ---- sort-4 ascending: (0,1)(2,3)(0,2)(1,3)(1,2) ----
        cswapd(cd[0], ci[0], cd[1], ci[1]);
        cswapd(cd[2], ci[2], cd[3], ci[3]);
        cswapd(cd[0], ci[0], cd[2], ci[2]);
        cswapd(cd[1], ci[1], cd[3], ci[3]);
        cswapd(cd[1], ci[1], cd[2], ci[2]);
        // ---- bitonic lowest-8 of sorted-8 U sorted-4: min phase ----
#pragma unroll
        for (int i = 0; i < 4; ++i) {
            const float db = cd[3 - i]; const int ib = ci[3 - i];
            const bool bl = db < bd[4 + i];
            bd[4 + i] = bl ? db : bd[4 + i];
            bi[4 + i] = bl ? ib : bi[4 + i];
        }
        // ---- bitonic-8 cleaner (restores ascending order) ----
        cswapd(bd[0], bi[0], bd[4], bi[4]);
        cswapd(bd[1], bi[1], bd[5], bi[5]);
        cswapd(bd[2], bi[2], bd[6], bi[6]);
        cswapd(bd[3], bi[3], bd[7], bi[7]);
        cswapd(bd[0], bi[0], bd[2], bi[2]);
        cswapd(bd[1], bi[1], bd[3], bi[3]);
        cswapd(bd[4], bi[4], bd[6], bi[6]);
        cswapd(bd[5], bi[5], bd[7], bi[7]);
        cswapd(bd[0], bi[0], bd[1], bi[1]);
        cswapd(bd[2], bi[2], bd[3], bi[3]);
        cswapd(bd[4], bi[4], bd[5], bi[5]);
        cswapd(bd[6], bi[6], bd[7], bi[7]);
    }
    // 3 shuffle merge rounds: partner = lane ^ r (same point, r in {1,2,4})
#pragma unroll
    for (int r = 1; r <= 4; r <<= 1) {
        float od[8]; int oi[8];
#pragma unroll
        for (int k = 0; k < 8; ++k) {
            od[k] = __shfl_xor(bd[k], r);
            oi[k] = __shfl_xor(bi[k], r);
        }
        float md[8]; int mi[8];
#pragma unroll
        for (int k = 0; k < 8; ++k) {           // lowest-8 of union (bitonic)
            const float da = bd[k], db = od[7 - k];
            const int   ia = bi[k], ib = oi[7 - k];
            const bool bl = (db < da) || (db == da && ib < ia);
            md[k] = bl ? db : da; mi[k] = bl ? ib : ia;
        }
#define CSM(a, c) cswap(md[a], mi[a], md[c], mi[c])
        CSM(0,4); CSM(1,5); CSM(2,6); CSM(3,7);
        CSM(0,2); CSM(1,3); CSM(4,6); CSM(5,7);
        CSM(0,1); CSM(2,3); CSM(4,5); CSM(6,7);
#undef CSM
#pragma unroll
        for (int k = 0; k < 8; ++k) { bd[k] = md[k]; bi[k] = mi[k]; }
    }
    if (seg == 0) {
        float nx = 0.f, ny = 0.f, nz = 0.f;
#pragma unroll
        for (int k = 0; k < 8; ++k) { const float4 q = sp[bi[k]]; nx += q.x; ny += q.y; nz += q.z; }
        const float s8 = 0.125f;
        float* ob = out + (size_t)b * 3 * Mn;
        ob[m]          = 2.f * p.x - nx * s8;
        ob[Mn + m]     = 2.f * p.y - ny * s8;
        ob[2 * Mn + m] = 2.f * p.z - nz * s8;
    }
}

// ============================================================================
extern "C" void kernel_launch(void* const* d_in, const int* in_sizes, int n_in,
                              void* d_out, int out_size, void* d_ws, size_t ws_size,
                              hipStream_t stream)
{
    (void)in_sizes; (void)n_in; (void)out_size;
    const float* z     = (const float*)d_in[0];
    const float* s     = (const float*)d_in[1];
    const float* w_m1  = (const float*)d_in[2];
    const float* b_m1  = (const float*)d_in[3];
    const float* w_m2  = (const float*)d_in[4];
    const float* b_m2  = (const float*)d_in[5];
    const float* w_out = (const float*)d_in[6];
    const float* b_out = (const float*)d_in[7];
    const float* w_c[4]  = {(const float*)d_in[8],  (const float*)d_in[12], (const float*)d_in[16], (const float*)d_in[20]};
    const float* b_c[4]  = {(const float*)d_in[9],  (const float*)d_in[13], (const float*)d_in[17], (const float*)d_in[21]};
    const float* g_c[4]  = {(const float*)d_in[10], (const float*)d_in[14], (const float*)d_in[18], (const float*)d_in[22]};
    const float* be_c[4] = {(const float*)d_in[11], (const float*)d_in[15], (const float*)d_in[19], (const float*)d_in[23]};

    char* ws = (char*)d_ws;
    const size_t MB = 1024ull * 1024ull;
    float* outp = (float*)d_out;
    if (ws_size < 208 * MB) return;   // proven: harness provides >= 208 MiB

    // -------- split-fp16 MFMA path (peak 204 MiB) --------
    u16*   wbuf  = (u16*)ws;
    float* stats = (float*)(ws + 3 * MB);
    u16*   xs  = (u16*)(ws + 4 * MB);
    u16*   x1  = (u16*)(ws + 12 * MB);
    u16*   x2  = (u16*)(ws + 76 * MB);
    u16*   y0  = (u16*)(ws + 12 * MB);   // contiguous after both chunks (RAW)
    u16*   y0a = (u16*)(ws + 12 * MB);   // rows [0, 32K)
    u16*   y0b = (u16*)(ws + 76 * MB);   // rows [32K, 64K)
    u16*   y1  = (u16*)(ws + 140 * MB);  // RAW c1 output
    u16*   y2  = (u16*)(ws + 12 * MB);   // RAW c2 output
    u16*   y3  = (u16*)(ws + 76 * MB);   // RAW c3 output
    float* pts = (float*)(ws + 4 * MB);

    prep_kernel<<<2497, 256, 0, stream>>>(w_m1, w_m2, w_c[0], w_c[1], w_c[2], w_c[3], s, wbuf, xs, stats);
    // m1: [N][32] -> [N][256]  (Ntiles=512, MY=2 -> 1024 blocks)
    mfma_gemm<2, 2, 0, 2, 0><<<1024, 256, 0, stream>>>(wbuf, xs, x1, b_m1, nullptr, nullptr, nullptr, nullptr, nullptr, 256, 32);
    // m2: [N][256] -> [N][512] (Ntiles=512, MY=4 -> 2048 blocks)
    mfma_gemm<2, 2, 1, 4, 0><<<2048, 256, 0, stream>>>(wbuf + 16384, x1, x2, b_m2, z, nullptr, nullptr, nullptr, nullptr, 512, 256);
    // c0 a/b: rows halves      (Ntiles=256, MY=4 -> 1024 blocks each) -> RAW y0 + stats
    mfma_gemm<2, 2, 2, 4, 0><<<1024, 256, 0, stream>>>(wbuf + 278528, x2, y0a, b_c[0], nullptr, nullptr, nullptr, nullptr, stats + 0, 512, 512);
    mfma_gemm<2, 2, 2, 4, 0><<<1024, 256, 0, stream>>>(wbuf + 278528, x2 + (size_t)Hn * 1024, y0b, b_c[0], nullptr, nullptr, nullptr, nullptr, stats + 0, 512, 512);
    // c1: BN0+ReLU fused on B-input (finalize folded: stats+0, g0, be0); RAW y1 + stats
    mfma_gemm<2, 2, 2, 2, 1><<<1024, 256, 0, stream>>>(wbuf + 802816, y0, y1, b_c[1], nullptr, stats + 0, g_c[0], be_c[0], stats + 1024, 256, 512);
    // c2: BN1+ReLU fused on B-input (stats+1024, g1, be1); RAW y2 + stats
    mfma_gemm<2, 2, 2, 1, 1><<<512, 256, 0, stream>>>(wbuf + 1064960, y1, y2, b_c[2], nullptr, stats + 1024, g_c[1], be_c[1], stats + 2048, 128, 256);
    // c3: BN2+ReLU fused on B-input (stats+2048, g2, be2); RAW y3 + stats
    mfma_gemm<1, 4, 2, 1, 1><<<256, 256, 0, stream>>>(wbuf + 1130496, y2, y3, b_c[3], nullptr, stats + 2048, g_c[2], be_c[2], stats + 3072, 64, 128);
    // final conv: BN3 finalize folded (stats+3072, g3, be3)
    finalconv_pm<<<Nn / 256, 256, 0, stream>>>(y3, stats + 3072, g_c[3], be_c[3], w_out, b_out, pts);
    knn_kernel<<<dim3(Mn / 64, Bn), 512, 0, stream>>>(pts, outp);
}

// Round 5
// 707.697 us; speedup vs baseline: 1.4009x; 1.2388x over previous
//
#include <hip/hip_runtime.h>
#include <math.h>

#define Bn 32
#define Mn 2048
#define Nn 65536      // Bn * Mn
#define Hn 32768      // Nn / 2 (chunk for race-free c0)
#define SDn 16
#define CWn 512
#define EPSf 1e-5f
#define KGF 8
#define WTOT 573440   // logical weight elements
#define LSC 2048.0f   // lo-plane scale (2^11)
#define LSCI (1.0f / 2048.0f)

typedef unsigned short u16;
typedef _Float16 fp16_t;
typedef __attribute__((ext_vector_type(8))) _Float16 h8v;  // MFMA A/B frag: 8 f16
typedef __attribute__((ext_vector_type(4))) float f4v;     // MFMA C/D frag: 4 fp32

__device__ __forceinline__ u16 f2h(float f) {
    union { fp16_t h; u16 u; } c; c.h = (fp16_t)f; return c.u;
}
__device__ __forceinline__ float h2f(u16 u) {
    union { fp16_t h; u16 u; } c; c.u = u; return (float)c.h;
}
__device__ __forceinline__ void fsplit(float f, u16& hi, u16& lo) {
    hi = f2h(f);
    lo = f2h((f - h2f(hi)) * LSC);
}
__device__ __forceinline__ float fjoin(u16 hi, u16 lo) {
    return h2f(hi) + h2f(lo) * LSCI;
}
// async global->LDS, 16 bytes/lane (dest must be wave-uniform base + lane*16)
__device__ __forceinline__ void gll16(const u16* g, u16* l) {
    __builtin_amdgcn_global_load_lds((const __attribute__((address_space(1))) void*)g,
                                     (__attribute__((address_space(3))) void*)l, 16, 0, 0);
}
// lexicographic comparator swap (merge tail): keep (d0,i0) <= (d1,i1)
__device__ __forceinline__ void cswap(float& d0, int& i0, float& d1, int& i1) {
    const bool gt = (d0 > d1) || (d0 == d1 && i0 > i1);
    const float ta = gt ? d1 : d0, tb = gt ? d0 : d1;
    const int   ua = gt ? i1 : i0, ub = gt ? i0 : i1;
    d0 = ta; d1 = tb; i0 = ua; i1 = ub;
}
// distance-only stable comparator swap (hot loop): swap iff d0 > d1 strictly
__device__ __forceinline__ void cswapd(float& d0, int& i0, float& d1, int& i1) {
    const bool gt = d0 > d1;
    const float ta = gt ? d1 : d0, tb = gt ? d0 : d1;
    const int   ua = gt ? i1 : i0, ub = gt ? i0 : i1;
    d0 = ta; d1 = tb; i0 = ua; i1 = ub;
}

// ============================================================================
// prep: weights fp32 -> split layout, normalize s -> xs, zero stats (fused)
// ============================================================================
__global__ __launch_bounds__(256) void prep_kernel(
    const float* __restrict__ wm1, const float* __restrict__ wm2,
    const float* __restrict__ wc0, const float* __restrict__ wc1,
    const float* __restrict__ wc2, const float* __restrict__ wc3,
    const float* __restrict__ s,
    u16* __restrict__ wbuf, u16* __restrict__ xs, float* __restrict__ stats)
{
    const int bid = blockIdx.x;
    const int tid = threadIdx.x;
    if (bid < 2240) {
        // ---- weight conversion: [Cout][hi[Cin] | lo[Cin]] ----
        int i = bid * 256 + tid;
        float w; int r, k, Cin; size_t base;
        if (i < 8192) {                              // m1 padded [256][32]
            r = i >> 5; k = i & 31; Cin = 32; base = 0;
            w = (k < SDn) ? wm1[r * SDn + k] : 0.f;
        } else {
            int j = i - 8192;
            if (j < 131072)                    { r = j >> 8; k = j & 255; Cin = 256; base = 16384;   w = wm2[j]; }
            else if ((j -= 131072) < 262144)   { r = j >> 9; k = j & 511; Cin = 512; base = 278528;  w = wc0[j]; }
            else if ((j -= 262144) < 131072)   { r = j >> 9; k = j & 511; Cin = 512; base = 802816;  w = wc1[j]; }
            else if ((j -= 131072) < 32768)    { r = j >> 8; k = j & 255; Cin = 256; base = 1064960; w = wc2[j]; }
            else { j -= 32768;                   r = j >> 7; k = j & 127; Cin = 128; base = 1130496; w = wc3[j]; }
        }
        const size_t addr = base + (size_t)r * (2 * Cin) + k;
        u16 hi, lo; fsplit(w, hi, lo);
        wbuf[addr] = hi;
        wbuf[addr + Cin] = lo;
    } else if (bid < 2496) {
        // ---- normalize s[B,16,M] -> xs[N][64] (hi[32]|lo[32], upper 16 zero)
        const int b2 = bid - 2240;
        const int m = (b2 & 7) * 256 + tid;
        const int b = b2 >> 3;
        const float* sp = s + (size_t)b * SDn * Mn + m;
        float v[SDn]; float sq = 0.f;
#pragma unroll
        for (int c = 0; c < SDn; ++c) { v[c] = sp[(size_t)c * Mn]; sq += v[c] * v[c]; }
        const float r = 1.0f / sqrtf(sq);
        unsigned int uh[8], ul[8];
#pragma unroll
        for (int c = 0; c < 8; ++c) {
            u16 h0, l0, h1, l1;
            fsplit(v[2 * c] * r, h0, l0);
            fsplit(v[2 * c + 1] * r, h1, l1);
            uh[c] = (unsigned int)h0 | ((unsigned int)h1 << 16);
            ul[c] = (unsigned int)l0 | ((unsigned int)l1 << 16);
        }
        uint4* xp = (uint4*)(xs + (size_t)(b * Mn + m) * 64);
        xp[0] = make_uint4(uh[0], uh[1], uh[2], uh[3]);
        xp[1] = make_uint4(uh[4], uh[5], uh[6], uh[7]);
        xp[2] = make_uint4(0, 0, 0, 0);
        xp[3] = make_uint4(0, 0, 0, 0);
        xp[4] = make_uint4(ul[0], ul[1], ul[2], ul[3]);
        xp[5] = make_uint4(ul[4], ul[5], ul[6], ul[7]);
        xp[6] = make_uint4(0, 0, 0, 0);
        xp[7] = make_uint4(0, 0, 0, 0);
    } else {
        // ---- zero BN stats (4096 floats) ----
        float4 z4 = {0.f, 0.f, 0.f, 0.f};
        float4* sp4 = (float4*)stats;
#pragma unroll
        for (int k = 0; k < 4; ++k) sp4[tid * 4 + k] = z4;
    }
}

// ---- split fp16 MFMA GEMM, async staging, XCD remap, swizzled LDS ----------
// acc0 = Wh*Xh ; accL = Wh*Xl' + Wl'*Xh ; result = acc0 + accL/2048
// IBN=1: BN(scale,shift)+ReLU fused on B-frags between LDS read and MFMA.
// BN finalize folded into the prologue (from producer stats/gamma/beta).
// Register budget: acc0+accL = 128 AGPRs; with launch_bounds(256,2) the
// total (arch+acc) must fit 256/wave -> 2 waves/SIMD -> 2 blocks/CU, giving
// cross-block overlap of the staging drain (was 1 block/CU at 284 regs,
// OccupancyPercent 10.6, MfmaUtil 13%). B-frags are read per-j (8 regs live
// instead of 32) to fit; per-accumulator MFMA order unchanged (bit-identical).
template<int RW, int CWv, int EPI, int MY, int IBN>
__global__ __launch_bounds__(256, 2) void mfma_gemm(
    const u16* __restrict__ W, const u16* __restrict__ X, u16* __restrict__ Y,
    const float* __restrict__ bias, const float* __restrict__ zmod,
    const float* __restrict__ bnst, const float* __restrict__ bng,
    const float* __restrict__ bnbe, float* __restrict__ stats, int Cout, int Cin)
{
    constexpr int BM = RW * 64, BN = CWv * 64;
    constexpr int ASEG = BM / 64, BSEG = BN / 64;
    constexpr int LMY = (MY == 1) ? 0 : (MY == 2) ? 1 : (MY == 4) ? 2 : 3;
    __shared__ __align__(16) u16 Ah[BM * 32], Al[BM * 32];
    __shared__ __align__(16) u16 Bh[BN * 32], Bl[BN * 32];
    __shared__ float sstat[(EPI == 2) ? (CWv * BM * 2) : 1];
    __shared__ __align__(16) float sbn[IBN ? 1024 : 4];   // (scale,shift) x Cin<=512

    const int tid = threadIdx.x;
    const int wave = tid >> 6;
    const int lane = tid & 63;
    const int wm = wave & (RW - 1), wn = wave / RW;
    const int l15 = lane & 15, q = lane >> 4;
    const int lin = blockIdx.x;
    const int xcd = lin & 7;
    const int jj = lin >> 3;
    const int m0 = (jj & (MY - 1)) * BM;
    const int n0 = (xcd + ((jj >> LMY) << 3)) * BN;
    const int SW = 2 * Cin;

    if constexpr (IBN) {
        const float inv = 1.0f / (float)Nn;
        for (int c = tid; c < Cin; c += 256) {
            const float mean = bnst[c * 2] * inv;
            const float var = bnst[c * 2 + 1] * inv - mean * mean;
            const float sc = bng[c] / sqrtf(var + EPSf);
            sbn[c * 2] = sc;
            sbn[c * 2 + 1] = fmaf(-mean, sc, bnbe[c]);
        }
        __syncthreads();
    }

    f4v acc0[4][4], accL[4][4];
#pragma unroll
    for (int i = 0; i < 4; ++i)
#pragma unroll
        for (int j = 0; j < 4; ++j) {
            acc0[i][j] = (f4v){0.f, 0.f, 0.f, 0.f};
            accL[i][j] = (f4v){0.f, 0.f, 0.f, 0.f};
        }

    const int nsteps = Cin >> 5;
    for (int ks = 0; ks < nsteps; ++ks) {
        const int k0 = ks << 5;
        __syncthreads();   // previous iteration's frag reads done before overwrite
#pragma unroll
        for (int s = 0; s < ASEG; ++s) {
            const int flat = s * 256 + tid;
            const int row = flat >> 2;
            const int qs = (flat & 3) ^ ((row >> 1) & 3);   // swizzled source chunk
            const u16* ga = W + (size_t)(m0 + row) * SW + k0 + qs * 8;
            gll16(ga, Ah + flat * 8);
            gll16(ga + Cin, Al + flat * 8);
        }
#pragma unroll
        for (int s = 0; s < BSEG; ++s) {
            const int flat = s * 256 + tid;
            const int row = flat >> 2;
            const int qs = (flat & 3) ^ ((row >> 1) & 3);
            const u16* gb = X + (size_t)(n0 + row) * SW + k0 + qs * 8;
            gll16(gb, Bh + flat * 8);
            gll16(gb + Cin, Bl + flat * 8);
        }
        __syncthreads();   // drains vmcnt -> LDS tiles ready
        h8v afh[4], afl[4];
#pragma unroll
        for (int i = 0; i < 4; ++i) {
            const int ar = wm * 64 + i * 16 + l15;
            const int ao = ar * 32 + ((q ^ ((ar >> 1) & 3)) << 3);
            afh[i] = *(const h8v*)(Ah + ao);
            afl[i] = *(const h8v*)(Al + ao);
        }
        float sc8[8], sh8[8];
        if constexpr (IBN) {
            // frag elems are LOGICAL channels k0 + q*8 + e (read-side XOR
            // undoes the swizzle), uniform across l15 -> broadcast LDS loads.
            const int kb = (k0 + q * 8) * 2;
            const float4 p0 = *(const float4*)(sbn + kb);
            const float4 p1 = *(const float4*)(sbn + kb + 4);
            const float4 p2 = *(const float4*)(sbn + kb + 8);
            const float4 p3 = *(const float4*)(sbn + kb + 12);
            sc8[0] = p0.x; sc8[1] = p0.z; sc8[2] = p1.x; sc8[3] = p1.z;
            sc8[4] = p2.x; sc8[5] = p2.z; sc8[6] = p3.x; sc8[7] = p3.z;
            sh8[0] = p0.y; sh8[1] = p0.w; sh8[2] = p1.y; sh8[3] = p1.w;
            sh8[4] = p2.y; sh8[5] = p2.w; sh8[6] = p3.y; sh8[7] = p3.w;
        }
#pragma unroll
        for (int j = 0; j < 4; ++j) {
            const int br = wn * 64 + j * 16 + l15;
            const int bo = br * 32 + ((q ^ ((br >> 1) & 3)) << 3);
            h8v bh = *(const h8v*)(Bh + bo);
            h8v bl = *(const h8v*)(Bl + bo);
            if constexpr (IBN) {
#pragma unroll
                for (int e = 0; e < 8; ++e) {
                    const float v = (float)bh[e] + (float)bl[e] * LSCI;
                    const float a = fmaxf(fmaf(v, sc8[e], sh8[e]), 0.f);
                    const fp16_t hh = (fp16_t)a;
                    bh[e] = hh;
                    bl[e] = (fp16_t)((a - (float)hh) * LSC);
                }
            }
#pragma unroll
            for (int i = 0; i < 4; ++i) {
                accL[i][j] = __builtin_amdgcn_mfma_f32_16x16x32_f16(afh[i], bl, accL[i][j], 0, 0, 0);
                accL[i][j] = __builtin_amdgcn_mfma_f32_16x16x32_f16(afl[i], bh, accL[i][j], 0, 0, 0);
                acc0[i][j] = __builtin_amdgcn_mfma_f32_16x16x32_f16(afh[i], bh, acc0[i][j], 0, 0, 0);
            }
        }
    }

    // ---- epilogue ----
    const int bb = n0 >> 11;
    const int SY = 2 * Cout;
#pragma unroll
    for (int i = 0; i < 4; ++i) {
        const int chb = m0 + wm * 64 + i * 16 + q * 4;
        const float4 bias4 = *(const float4*)(bias + chb);
        float z0 = 0.f, z1 = 0.f, z2 = 0.f, z3 = 0.f;
        if constexpr (EPI == 1) {
            const float4 z4 = *(const float4*)(zmod + bb * CWn + chb);
            z0 = z4.x; z1 = z4.y; z2 = z4.z; z3 = z4.w;
        }
        float ssum[4] = {0.f, 0.f, 0.f, 0.f}, ssq[4] = {0.f, 0.f, 0.f, 0.f};
#pragma unroll
        for (int j = 0; j < 4; ++j) {
            const int n = n0 + wn * 64 + j * 16 + l15;
            float v0 = fmaf(accL[i][j][0], LSCI, acc0[i][j][0]) + bias4.x;
            float v1 = fmaf(accL[i][j][1], LSCI, acc0[i][j][1]) + bias4.y;
            float v2 = fmaf(accL[i][j][2], LSCI, acc0[i][j][2]) + bias4.z;
            float v3 = fmaf(accL[i][j][3], LSCI, acc0[i][j][3]) + bias4.w;
            if constexpr (EPI == 0) {
                v0 = fmaxf(v0, 0.f); v1 = fmaxf(v1, 0.f); v2 = fmaxf(v2, 0.f); v3 = fmaxf(v3, 0.f);
            } else if constexpr (EPI == 1) {
                v0 = fminf(fmaxf(v0, -1.f), 1.f) * z0;
                v1 = fminf(fmaxf(v1, -1.f), 1.f) * z1;
                v2 = fminf(fmaxf(v2, -1.f), 1.f) * z2;
                v3 = fminf(fmaxf(v3, -1.f), 1.f) * z3;
            } else {
                ssum[0] += v0; ssum[1] += v1; ssum[2] += v2; ssum[3] += v3;
                ssq[0] += v0 * v0; ssq[1] += v1 * v1; ssq[2] += v2 * v2; ssq[3] += v3 * v3;
            }
            u16 h0, l0, h1, l1, h2, l2, h3, l3;
            fsplit(v0, h0, l0); fsplit(v1, h1, l1);
            fsplit(v2, h2, l2); fsplit(v3, h3, l3);
            ushort4 hv = {h0, h1, h2, h3};
            ushort4 lv = {l0, l1, l2, l3};
            u16* yp = Y + (size_t)n * SY + chb;
            *(ushort4*)yp = hv;
            *(ushort4*)(yp + Cout) = lv;
        }
        if constexpr (EPI == 2) {
#pragma unroll
            for (int r = 0; r < 4; ++r) {
#pragma unroll
                for (int d = 1; d < 16; d <<= 1) {
                    ssum[r] += __shfl_xor(ssum[r], d);
                    ssq[r]  += __shfl_xor(ssq[r], d);
                }
            }
            if (l15 == 0) {
                const int chl = wm * 64 + i * 16 + q * 4;
#pragma unroll
                for (int r = 0; r < 4; ++r) {
                    sstat[(wn * BM + chl + r) * 2]     = ssum[r];
                    sstat[(wn * BM + chl + r) * 2 + 1] = ssq[r];
                }
            }
        }
    }
    if constexpr (EPI == 2) {
        __syncthreads();
        if (tid < BM) {
            float s0 = 0.f, s1 = 0.f;
#pragma unroll
            for (int w = 0; w < CWv; ++w) {
                s0 += sstat[(w * BM + tid) * 2];
                s1 += sstat[(w * BM + tid) * 2 + 1];
            }
            atomicAdd(&stats[(m0 + tid) * 2], s0);
            atomicAdd(&stats[(m0 + tid) * 2 + 1], s1);
        }
    }
}

// ---- final 64->3 conv (BN finalize folded in; BN+ReLU on split input) ------
__global__ __launch_bounds__(256) void finalconv_pm(
    const u16* __restrict__ y3, const float* __restrict__ stats,
    const float* __restrict__ g, const float* __restrict__ be,
    const float* __restrict__ wout, const float* __restrict__ bout,
    float* __restrict__ pts)
{
    __shared__ float swo[3][64];
    __shared__ float ssc[64], ssh[64];
    const int tid = threadIdx.x;
    if (tid < 192) swo[tid / 64][tid % 64] = wout[tid];
    if (tid < 64) {
        const float inv = 1.0f / (float)Nn;
        const float mean = stats[tid * 2] * inv;
        const float var = stats[tid * 2 + 1] * inv - mean * mean;
        const float sc = g[tid] / sqrtf(var + EPSf);
        ssc[tid] = sc;
        ssh[tid] = fmaf(-mean, sc, be[tid]);
    }
    __syncthreads();
    const int n = blockIdx.x * 256 + tid;
    const uint4* yph = (const uint4*)(y3 + (size_t)n * 128);
    float d0 = bout[0], d1 = bout[1], d2 = bout[2];
#pragma unroll
    for (int cc = 0; cc < 8; ++cc) {
        const uint4 H = yph[cc];
        const uint4 L = yph[8 + cc];
        const unsigned hu[4] = {H.x, H.y, H.z, H.w};
        const unsigned lu[4] = {L.x, L.y, L.z, L.w};
#pragma unroll
        for (int e = 0; e < 4; ++e) {
            const int c = cc * 8 + e * 2;
            const float v0 = fjoin((u16)(hu[e] & 0xffff), (u16)(lu[e] & 0xffff));
            const float v1 = fjoin((u16)(hu[e] >> 16), (u16)(lu[e] >> 16));
            const float a0 = fmaxf(fmaf(v0, ssc[c], ssh[c]), 0.f);
            const float a1 = fmaxf(fmaf(v1, ssc[c + 1], ssh[c + 1]), 0.f);
            d0 = fmaf(a0, swo[0][c], d0); d0 = fmaf(a1, swo[0][c + 1], d0);
            d1 = fmaf(a0, swo[1][c], d1); d1 = fmaf(a1, swo[1][c + 1], d1);
            d2 = fmaf(a0, swo[2][c], d2); d2 = fmaf(a1, swo[2][c + 1], d2);
        }
    }
    float4 p = {d0, d1, d2, d0 * d0 + d1 * d1 + d2 * d2};
    *(float4*)(pts + (size_t)n * 4) = p;
}

// ---- graph filtering: 8 threads/point, batch-4 sorting-network insert ------
// Exact top-8 by strict-d comparators (tie order within a thread differs
// from scan-order insert, but exact-key ties are coordinate duplicates --
// validated rounds 0/1: different tie-break rules, identical output).
__global__ __launch_bounds__(512) void knn_kernel(const float* __restrict__ pts,
                                                  float* __restrict__ out) {
    __shared__ __align__(16) float4 sp[Mn];   // 32 KB -> 4 blocks/CU (wave cap)
    const int b = blockIdx.y;
    const int tid = threadIdx.x;
    const float4* pb = (const float4*)pts + (size_t)b * Mn;
    for (int i = tid; i < Mn; i += 512) sp[i] = pb[i];
    __syncthreads();
    const int lane = tid & 63;
    const int wv = tid >> 6;                    // 0..7
    const int seg = lane & 7;                   // segment 0..7
    const int ptl = (wv << 3) | (lane >> 3);    // point-local 0..63
    const int m = blockIdx.x * 64 + ptl;
    const float4 p = sp[m];
    float bd[8]; int bi[8];
#pragma unroll
    for (int k = 0; k < 8; ++k) { bd[k] = 1e30f; bi[k] = 0x7fffffff; }
    const int nb = seg << 8;
    for (int t = 0; t < 256; t += 4) {
        // ---- load 4 candidates, compute keys ----
        float cd[4]; int ci[4];
#pragma unroll
        for (int i = 0; i < 4; ++i) {
            const int n = nb | ((t + seg + i) & 255);   // stagger by seg (bank tiling)
            const float4 q = sp[n];
            const float dot = fmaf(p.x, q.x, fmaf(p.y, q.y, p.z * q.z));
            float d = fmaf(-2.f, dot, q.w);             // key = dist - p.w (monotone)
            d = (n == m) ? 1e30f : d;                   // exclude self
            cd[i] = d; ci[i] = n;
        }
        // ---- sort-4 ascending: (0,1)(2,3)(0,2)(1,3)(1,2) ----
        cswapd(cd[0], ci[0], cd[1], ci[1]);
        cswapd(cd[2], ci[2], cd[3], ci[3]);
        cswapd(cd[0], ci[0], cd[2], ci[2]);
        cswapd(cd[1], ci[1], cd[3], ci[3]);
        cswapd(cd[1], ci[1], cd[2], ci[2]);
        // ---- bitonic lowest-8 of sorted-8 U sorted-4: min phase ----
#pragma unroll
        for (int i = 0; i < 4; ++i) {
            const float db = cd[3 - i]; const int ib = ci[3 - i];
            const bool bl = db < bd[4 + i];
            bd[4 + i] = bl ? db : bd[4 + i];
            bi[4 + i] = bl ? ib : bi[4 + i];
        }
        // ---- bitonic-8 cleaner (restores ascending order) ----
        cswapd(bd[0], bi[0], bd[4], bi[4]);
        cswapd(bd[1], bi[1], bd[5], bi[5]);
        cswapd(bd[2], bi[2], bd[6], bi[6]);
        cswapd(bd[3], bi[3], bd[7], bi[7]);
        cswapd(bd[0], bi[0], bd[2], bi[2]);
        cswapd(bd[1], bi[1], bd[3], bi[3]);
        cswapd(bd[4], bi[4], bd[6], bi[6]);
        cswapd(bd[5], bi[5], bd[7], bi[7]);
        cswapd(bd[0], bi[0], bd[1], bi[1]);
        cswapd(bd[2], bi[2], bd[3], bi[3]);
        cswapd(bd[4], bi[4], bd[5], bi[5]);
        cswapd(bd[6], bi[6], bd[7], bi[7]);
    }
    // 3 shuffle merge rounds: partner = lane ^ r (same point, r in {1,2,4})
#pragma unroll
    for (int r = 1; r <= 4; r <<= 1) {
        float od[8]; int oi[8];
#pragma unroll
        for (int k = 0; k < 8; ++k) {
            od[k] = __shfl_xor(bd[k], r);
            oi[k] = __shfl_xor(bi[k], r);
        }
        float md[8]; int mi[8];
#pragma unroll
        for (int k = 0; k < 8; ++k) {           // lowest-8 of union (bitonic)
            const float da = bd[k], db = od[7 - k];
            const int   ia = bi[k], ib = oi[7 - k];
            const bool bl = (db < da) || (db == da && ib < ia);
            md[k] = bl ? db : da; mi[k] = bl ? ib : ia;
        }
#define CSM(a, c) cswap(md[a], mi[a], md[c], mi[c])
        CSM(0,4); CSM(1,5); CSM(2,6); CSM(3,7);
        CSM(0,2); CSM(1,3); CSM(4,6); CSM(5,7);
        CSM(0,1); CSM(2,3); CSM(4,5); CSM(6,7);
#undef CSM
#pragma unroll
        for (int k = 0; k < 8; ++k) { bd[k] = md[k]; bi[k] = mi[k]; }
    }
    if (seg == 0) {
        float nx = 0.f, ny = 0.f, nz = 0.f;
#pragma unroll
        for (int k = 0; k < 8; ++k) { const float4 q = sp[bi[k]]; nx += q.x; ny += q.y; nz += q.z; }
        const float s8 = 0.125f;
        float* ob = out + (size_t)b * 3 * Mn;
        ob[m]          = 2.f * p.x - nx * s8;
        ob[Mn + m]     = 2.f * p.y - ny * s8;
        ob[2 * Mn + m] = 2.f * p.z - nz * s8;
    }
}

// ============================================================================
extern "C" void kernel_launch(void* const* d_in, const int* in_sizes, int n_in,
                              void* d_out, int out_size, void* d_ws, size_t ws_size,
                              hipStream_t stream)
{
    (void)in_sizes; (void)n_in; (void)out_size;
    const float* z     = (const float*)d_in[0];
    const float* s     = (const float*)d_in[1];
    const float* w_m1  = (const float*)d_in[2];
    const float* b_m1  = (const float*)d_in[3];
    const float* w_m2  = (const float*)d_in[4];
    const float* b_m2  = (const float*)d_in[5];
    const float* w_out = (const float*)d_in[6];
    const float* b_out = (const float*)d_in[7];
    const float* w_c[4]  = {(const float*)d_in[8],  (const float*)d_in[12], (const float*)d_in[16], (const float*)d_in[20]};
    const float* b_c[4]  = {(const float*)d_in[9],  (const float*)d_in[13], (const float*)d_in[17], (const float*)d_in[21]};
    const float* g_c[4]  = {(const float*)d_in[10], (const float*)d_in[14], (const float*)d_in[18], (const float*)d_in[22]};
    const float* be_c[4] = {(const float*)d_in[11], (const float*)d_in[15], (const float*)d_in[19], (const float*)d_in[23]};

    char* ws = (char*)d_ws;
    const size_t MB = 1024ull * 1024ull;
    float* outp = (float*)d_out;
    if (ws_size < 208 * MB) return;   // proven: harness provides >= 208 MiB

    // -------- split-fp16 MFMA path (peak 204 MiB) --------
    u16*   wbuf  = (u16*)ws;
    float* stats = (float*)(ws + 3 * MB);
    u16*   xs  = (u16*)(ws + 4 * MB);
    u16*   x1  = (u16*)(ws + 12 * MB);
    u16*   x2  = (u16*)(ws + 76 * MB);
    u16*   y0  = (u16*)(ws + 12 * MB);   // contiguous after both chunks (RAW)
    u16*   y0a = (u16*)(ws + 12 * MB);   // rows [0, 32K)
    u16*   y0b = (u16*)(ws + 76 * MB);   // rows [32K, 64K)
    u16*   y1  = (u16*)(ws + 140 * MB);  // RAW c1 output
    u16*   y2  = (u16*)(ws + 12 * MB);   // RAW c2 output
    u16*   y3  = (u16*)(ws + 76 * MB);   // RAW c3 output
    float* pts = (float*)(ws + 4 * MB);

    prep_kernel<<<2497, 256, 0, stream>>>(w_m1, w_m2, w_c[0], w_c[1], w_c[2], w_c[3], s, wbuf, xs, stats);
    // m1: [N][32] -> [N][256]  (Ntiles=512, MY=2 -> 1024 blocks)
    mfma_gemm<2, 2, 0, 2, 0><<<1024, 256, 0, stream>>>(wbuf, xs, x1, b_m1, nullptr, nullptr, nullptr, nullptr, nullptr, 256, 32);
    // m2: [N][256] -> [N][512] (Ntiles=512, MY=4 -> 2048 blocks)
    mfma_gemm<2, 2, 1, 4, 0><<<2048, 256, 0, stream>>>(wbuf + 16384, x1, x2, b_m2, z, nullptr, nullptr, nullptr, nullptr, 512, 256);
    // c0 a/b: rows halves      (Ntiles=256, MY=4 -> 1024 blocks each) -> RAW y0 + stats
    mfma_gemm<2, 2, 2, 4, 0><<<1024, 256, 0, stream>>>(wbuf + 278528, x2, y0a, b_c[0], nullptr, nullptr, nullptr, nullptr, stats + 0, 512, 512);
    mfma_gemm<2, 2, 2, 4, 0><<<1024, 256, 0, stream>>>(wbuf + 278528, x2 + (size_t)Hn * 1024, y0b, b_c[0], nullptr, nullptr, nullptr, nullptr, stats + 0, 512, 512);
    // c1: BN0+ReLU fused on B-input (finalize folded: stats+0, g0, be0); RAW y1 + stats
    mfma_gemm<2, 2, 2, 2, 1><<<1024, 256, 0, stream>>>(wbuf + 802816, y0, y1, b_c[1], nullptr, stats + 0, g_c[0], be_c[0], stats + 1024, 256, 512);
    // c2: BN1+ReLU fused on B-input (stats+1024, g1, be1); RAW y2 + stats
    mfma_gemm<2, 2, 2, 1, 1><<<512, 256, 0, stream>>>(wbuf + 1064960, y1, y2, b_c[2], nullptr, stats + 1024, g_c[1], be_c[1], stats + 2048, 128, 256);
    // c3: BN2+ReLU fused on B-input (stats+2048, g2, be2); RAW y3 + stats
    mfma_gemm<1, 4, 2, 1, 1><<<256, 256, 0, stream>>>(wbuf + 1130496, y2, y3, b_c[3], nullptr, stats + 2048, g_c[2], be_c[2], stats + 3072, 64, 128);
    // final conv: BN3 finalize folded (stats+3072, g3, be3)
    finalconv_pm<<<Nn / 256, 256, 0, stream>>>(y3, stats + 3072, g_c[3], be_c[3], w_out, b_out, pts);
    knn_kernel<<<dim3(Mn / 64, Bn), 512, 0, stream>>>(pts, outp);
}

// Round 6
// 672.549 us; speedup vs baseline: 1.4741x; 1.0523x over previous
//
#include <hip/hip_runtime.h>
#include <math.h>

#define Bn 32
#define Mn 2048
#define Nn 65536      // Bn * Mn
#define Hn 32768      // Nn / 2 (chunk for race-free c0)
#define SDn 16
#define CWn 512
#define EPSf 1e-5f
#define KGF 8
#define WTOT 573440   // logical weight elements
#define LSC 2048.0f   // lo-plane scale (2^11)
#define LSCI (1.0f / 2048.0f)

typedef unsigned short u16;
typedef _Float16 fp16_t;
typedef __attribute__((ext_vector_type(8))) _Float16 h8v;  // MFMA A/B frag: 8 f16
typedef __attribute__((ext_vector_type(4))) float f4v;     // MFMA C/D frag: 4 fp32

__device__ __forceinline__ u16 f2h(float f) {
    union { fp16_t h; u16 u; } c; c.h = (fp16_t)f; return c.u;
}
__device__ __forceinline__ float h2f(u16 u) {
    union { fp16_t h; u16 u; } c; c.u = u; return (float)c.h;
}
__device__ __forceinline__ void fsplit(float f, u16& hi, u16& lo) {
    hi = f2h(f);
    lo = f2h((f - h2f(hi)) * LSC);
}
__device__ __forceinline__ float fjoin(u16 hi, u16 lo) {
    return h2f(hi) + h2f(lo) * LSCI;
}
// async global->LDS, 16 bytes/lane (dest must be wave-uniform base + lane*16)
__device__ __forceinline__ void gll16(const u16* g, u16* l) {
    __builtin_amdgcn_global_load_lds((const __attribute__((address_space(1))) void*)g,
                                     (__attribute__((address_space(3))) void*)l, 16, 0, 0);
}
// lexicographic comparator swap (merge tail): keep (d0,i0) <= (d1,i1)
__device__ __forceinline__ void cswap(float& d0, int& i0, float& d1, int& i1) {
    const bool gt = (d0 > d1) || (d0 == d1 && i0 > i1);
    const float ta = gt ? d1 : d0, tb = gt ? d0 : d1;
    const int   ua = gt ? i1 : i0, ub = gt ? i0 : i1;
    d0 = ta; d1 = tb; i0 = ua; i1 = ub;
}
// distance-only stable comparator swap (hot loop): swap iff d0 > d1 strictly
__device__ __forceinline__ void cswapd(float& d0, int& i0, float& d1, int& i1) {
    const bool gt = d0 > d1;
    const float ta = gt ? d1 : d0, tb = gt ? d0 : d1;
    const int   ua = gt ? i1 : i0, ub = gt ? i0 : i1;
    d0 = ta; d1 = tb; i0 = ua; i1 = ub;
}

// ============================================================================
// prep: weights fp32 -> split layout, normalize s -> xs, zero stats (fused)
// ============================================================================
__global__ __launch_bounds__(256) void prep_kernel(
    const float* __restrict__ wm1, const float* __restrict__ wm2,
    const float* __restrict__ wc0, const float* __restrict__ wc1,
    const float* __restrict__ wc2, const float* __restrict__ wc3,
    const float* __restrict__ s,
    u16* __restrict__ wbuf, u16* __restrict__ xs, float* __restrict__ stats)
{
    const int bid = blockIdx.x;
    const int tid = threadIdx.x;
    if (bid < 2240) {
        // ---- weight conversion: [Cout][hi[Cin] | lo[Cin]] ----
        int i = bid * 256 + tid;
        float w; int r, k, Cin; size_t base;
        if (i < 8192) {                              // m1 padded [256][32]
            r = i >> 5; k = i & 31; Cin = 32; base = 0;
            w = (k < SDn) ? wm1[r * SDn + k] : 0.f;
        } else {
            int j = i - 8192;
            if (j < 131072)                    { r = j >> 8; k = j & 255; Cin = 256; base = 16384;   w = wm2[j]; }
            else if ((j -= 131072) < 262144)   { r = j >> 9; k = j & 511; Cin = 512; base = 278528;  w = wc0[j]; }
            else if ((j -= 262144) < 131072)   { r = j >> 9; k = j & 511; Cin = 512; base = 802816;  w = wc1[j]; }
            else if ((j -= 131072) < 32768)    { r = j >> 8; k = j & 255; Cin = 256; base = 1064960; w = wc2[j]; }
            else { j -= 32768;                   r = j >> 7; k = j & 127; Cin = 128; base = 1130496; w = wc3[j]; }
        }
        const size_t addr = base + (size_t)r * (2 * Cin) + k;
        u16 hi, lo; fsplit(w, hi, lo);
        wbuf[addr] = hi;
        wbuf[addr + Cin] = lo;
    } else if (bid < 2496) {
        // ---- normalize s[B,16,M] -> xs[N][64] (hi[32]|lo[32], upper 16 zero)
        const int b2 = bid - 2240;
        const int m = (b2 & 7) * 256 + tid;
        const int b = b2 >> 3;
        const float* sp = s + (size_t)b * SDn * Mn + m;
        float v[SDn]; float sq = 0.f;
#pragma unroll
        for (int c = 0; c < SDn; ++c) { v[c] = sp[(size_t)c * Mn]; sq += v[c] * v[c]; }
        const float r = 1.0f / sqrtf(sq);
        unsigned int uh[8], ul[8];
#pragma unroll
        for (int c = 0; c < 8; ++c) {
            u16 h0, l0, h1, l1;
            fsplit(v[2 * c] * r, h0, l0);
            fsplit(v[2 * c + 1] * r, h1, l1);
            uh[c] = (unsigned int)h0 | ((unsigned int)h1 << 16);
            ul[c] = (unsigned int)l0 | ((unsigned int)l1 << 16);
        }
        uint4* xp = (uint4*)(xs + (size_t)(b * Mn + m) * 64);
        xp[0] = make_uint4(uh[0], uh[1], uh[2], uh[3]);
        xp[1] = make_uint4(uh[4], uh[5], uh[6], uh[7]);
        xp[2] = make_uint4(0, 0, 0, 0);
        xp[3] = make_uint4(0, 0, 0, 0);
        xp[4] = make_uint4(ul[0], ul[1], ul[2], ul[3]);
        xp[5] = make_uint4(ul[4], ul[5], ul[6], ul[7]);
        xp[6] = make_uint4(0, 0, 0, 0);
        xp[7] = make_uint4(0, 0, 0, 0);
    } else {
        // ---- zero BN stats (4096 floats) ----
        float4 z4 = {0.f, 0.f, 0.f, 0.f};
        float4* sp4 = (float4*)stats;
#pragma unroll
        for (int k = 0; k < 4; ++k) sp4[tid * 4 + k] = z4;
    }
}

// ---- split fp16 MFMA GEMM, async staging, XCD remap, swizzled LDS ----------
// acc0 = Wh*Xh ; accL = Wh*Xl' + Wl'*Xh ; result = acc0 + accL/2048
// IBN=1: BN(scale,shift)+ReLU fused on B-frags between LDS read and MFMA.
// BN finalize folded into the prologue (from producer stats/gamma/beta).
// launch_bounds(256,2): 2 waves/SIMD (2 blocks/CU) for cross-block overlap.
// CIN is a template param -> K-loop fully unrolled: global staging collapses
// to 2 loop-invariant bases + immediate offsets (stride 64B/step, lo-plane
// +2*CIN B, max ~2KB < 13-bit field), LDS frag addresses computed once,
// IBN table reads at immediate offsets. Removes ~80-100 VALU ops/thread/step
// of address recomputation; arithmetic order unchanged (bit-identical).
template<int RW, int CWv, int EPI, int MY, int IBN, int CIN>
__global__ __launch_bounds__(256, 2) void mfma_gemm(
    const u16* __restrict__ W, const u16* __restrict__ X, u16* __restrict__ Y,
    const float* __restrict__ bias, const float* __restrict__ zmod,
    const float* __restrict__ bnst, const float* __restrict__ bng,
    const float* __restrict__ bnbe, float* __restrict__ stats, int Cout)
{
    constexpr int Cin = CIN;
    constexpr int BM = RW * 64, BN = CWv * 64;
    constexpr int ASEG = BM / 64, BSEG = BN / 64;
    constexpr int LMY = (MY == 1) ? 0 : (MY == 2) ? 1 : (MY == 4) ? 2 : 3;
    constexpr int SW = 2 * Cin;
    constexpr int nsteps = Cin >> 5;
    __shared__ __align__(16) u16 Ah[BM * 32], Al[BM * 32];
    __shared__ __align__(16) u16 Bh[BN * 32], Bl[BN * 32];
    __shared__ float sstat[(EPI == 2) ? (CWv * BM * 2) : 1];
    __shared__ __align__(16) float sbn[IBN ? 1024 : 4];   // (scale,shift) x Cin<=512

    const int tid = threadIdx.x;
    const int wave = tid >> 6;
    const int lane = tid & 63;
    const int wm = wave & (RW - 1), wn = wave / RW;
    const int l15 = lane & 15, q = lane >> 4;
    const int lin = blockIdx.x;
    const int xcd = lin & 7;
    const int jj = lin >> 3;
    const int m0 = (jj & (MY - 1)) * BM;
    const int n0 = (xcd + ((jj >> LMY) << 3)) * BN;

    if constexpr (IBN) {
        const float inv = 1.0f / (float)Nn;
#pragma unroll
        for (int c0i = 0; c0i < Cin; c0i += 256) {
            const int c = c0i + tid;
            const float mean = bnst[c * 2] * inv;
            const float var = bnst[c * 2 + 1] * inv - mean * mean;
            const float sc = bng[c] / sqrtf(var + EPSf);
            sbn[c * 2] = sc;
            sbn[c * 2 + 1] = fmaf(-mean, sc, bnbe[c]);
        }
        __syncthreads();
    }

    f4v acc0[4][4], accL[4][4];
#pragma unroll
    for (int i = 0; i < 4; ++i)
#pragma unroll
        for (int j = 0; j < 4; ++j) {
            acc0[i][j] = (f4v){0.f, 0.f, 0.f, 0.f};
            accL[i][j] = (f4v){0.f, 0.f, 0.f, 0.f};
        }

    // loop-invariant staging bases (k0 enters as an immediate offset)
    const int aflat = tid;                 // used with s*256 offsets
    const int arow = tid >> 2;
    const int aqs = (tid & 3) ^ ((arow >> 1) & 3);
    // per-seg source bases
    const u16* gaB[ASEG];
    const u16* gbB[BSEG];
#pragma unroll
    for (int s = 0; s < ASEG; ++s) {
        const int flat = s * 256 + tid;
        const int row = flat >> 2;
        const int qs = (flat & 3) ^ ((row >> 1) & 3);
        gaB[s] = W + (size_t)(m0 + row) * SW + qs * 8;
    }
#pragma unroll
    for (int s = 0; s < BSEG; ++s) {
        const int flat = s * 256 + tid;
        const int row = flat >> 2;
        const int qs = (flat & 3) ^ ((row >> 1) & 3);
        gbB[s] = X + (size_t)(n0 + row) * SW + qs * 8;
    }
    // loop-invariant LDS frag offsets
    int aoff[4], boff[4];
#pragma unroll
    for (int i = 0; i < 4; ++i) {
        const int ar = wm * 64 + i * 16 + l15;
        aoff[i] = ar * 32 + ((q ^ ((ar >> 1) & 3)) << 3);
    }
#pragma unroll
    for (int j = 0; j < 4; ++j) {
        const int br = wn * 64 + j * 16 + l15;
        boff[j] = br * 32 + ((q ^ ((br >> 1) & 3)) << 3);
    }

#pragma unroll
    for (int ks = 0; ks < nsteps; ++ks) {
        const int k0 = ks << 5;
        __syncthreads();   // previous iteration's frag reads done before overwrite
#pragma unroll
        for (int s = 0; s < ASEG; ++s) {
            const int flat = s * 256 + tid;
            const u16* ga = gaB[s] + k0;
            gll16(ga, Ah + flat * 8);
            gll16(ga + Cin, Al + flat * 8);
        }
#pragma unroll
        for (int s = 0; s < BSEG; ++s) {
            const int flat = s * 256 + tid;
            const u16* gb = gbB[s] + k0;
            gll16(gb, Bh + flat * 8);
            gll16(gb + Cin, Bl + flat * 8);
        }
        __syncthreads();   // drains vmcnt -> LDS tiles ready
        h8v afh[4], afl[4];
#pragma unroll
        for (int i = 0; i < 4; ++i) {
            afh[i] = *(const h8v*)(Ah + aoff[i]);
            afl[i] = *(const h8v*)(Al + aoff[i]);
        }
        float sc8[8], sh8[8];
        if constexpr (IBN) {
            // frag elems are LOGICAL channels k0 + q*8 + e (read-side XOR
            // undoes the swizzle), uniform across l15 -> broadcast LDS loads.
            const int kb = (k0 + q * 8) * 2;
            const float4 p0 = *(const float4*)(sbn + kb);
            const float4 p1 = *(const float4*)(sbn + kb + 4);
            const float4 p2 = *(const float4*)(sbn + kb + 8);
            const float4 p3 = *(const float4*)(sbn + kb + 12);
            sc8[0] = p0.x; sc8[1] = p0.z; sc8[2] = p1.x; sc8[3] = p1.z;
            sc8[4] = p2.x; sc8[5] = p2.z; sc8[6] = p3.x; sc8[7] = p3.z;
            sh8[0] = p0.y; sh8[1] = p0.w; sh8[2] = p1.y; sh8[3] = p1.w;
            sh8[4] = p2.y; sh8[5] = p2.w; sh8[6] = p3.y; sh8[7] = p3.w;
        }
#pragma unroll
        for (int j = 0; j < 4; ++j) {
            h8v bh = *(const h8v*)(Bh + boff[j]);
            h8v bl = *(const h8v*)(Bl + boff[j]);
            if constexpr (IBN) {
#pragma unroll
                for (int e = 0; e < 8; ++e) {
                    const float v = (float)bh[e] + (float)bl[e] * LSCI;
                    const float a = fmaxf(fmaf(v, sc8[e], sh8[e]), 0.f);
                    const fp16_t hh = (fp16_t)a;
                    bh[e] = hh;
                    bl[e] = (fp16_t)((a - (float)hh) * LSC);
                }
            }
#pragma unroll
            for (int i = 0; i < 4; ++i) {
                accL[i][j] = __builtin_amdgcn_mfma_f32_16x16x32_f16(afh[i], bl, accL[i][j], 0, 0, 0);
                accL[i][j] = __builtin_amdgcn_mfma_f32_16x16x32_f16(afl[i], bh, accL[i][j], 0, 0, 0);
                acc0[i][j] = __builtin_amdgcn_mfma_f32_16x16x32_f16(afh[i], bh, acc0[i][j], 0, 0, 0);
            }
        }
    }

    // ---- epilogue ----
    const int bb = n0 >> 11;
    const int SY = 2 * Cout;
#pragma unroll
    for (int i = 0; i < 4; ++i) {
        const int chb = m0 + wm * 64 + i * 16 + q * 4;
        const float4 bias4 = *(const float4*)(bias + chb);
        float z0 = 0.f, z1 = 0.f, z2 = 0.f, z3 = 0.f;
        if constexpr (EPI == 1) {
            const float4 z4 = *(const float4*)(zmod + bb * CWn + chb);
            z0 = z4.x; z1 = z4.y; z2 = z4.z; z3 = z4.w;
        }
        float ssum[4] = {0.f, 0.f, 0.f, 0.f}, ssq[4] = {0.f, 0.f, 0.f, 0.f};
#pragma unroll
        for (int j = 0; j < 4; ++j) {
            const int n = n0 + wn * 64 + j * 16 + l15;
            float v0 = fmaf(accL[i][j][0], LSCI, acc0[i][j][0]) + bias4.x;
            float v1 = fmaf(accL[i][j][1], LSCI, acc0[i][j][1]) + bias4.y;
            float v2 = fmaf(accL[i][j][2], LSCI, acc0[i][j][2]) + bias4.z;
            float v3 = fmaf(accL[i][j][3], LSCI, acc0[i][j][3]) + bias4.w;
            if constexpr (EPI == 0) {
                v0 = fmaxf(v0, 0.f); v1 = fmaxf(v1, 0.f); v2 = fmaxf(v2, 0.f); v3 = fmaxf(v3, 0.f);
            } else if constexpr (EPI == 1) {
                v0 = fminf(fmaxf(v0, -1.f), 1.f) * z0;
                v1 = fminf(fmaxf(v1, -1.f), 1.f) * z1;
                v2 = fminf(fmaxf(v2, -1.f), 1.f) * z2;
                v3 = fminf(fmaxf(v3, -1.f), 1.f) * z3;
            } else {
                ssum[0] += v0; ssum[1] += v1; ssum[2] += v2; ssum[3] += v3;
                ssq[0] += v0 * v0; ssq[1] += v1 * v1; ssq[2] += v2 * v2; ssq[3] += v3 * v3;
            }
            u16 h0, l0, h1, l1, h2, l2, h3, l3;
            fsplit(v0, h0, l0); fsplit(v1, h1, l1);
            fsplit(v2, h2, l2); fsplit(v3, h3, l3);
            ushort4 hv = {h0, h1, h2, h3};
            ushort4 lv = {l0, l1, l2, l3};
            u16* yp = Y + (size_t)n * SY + chb;
            *(ushort4*)yp = hv;
            *(ushort4*)(yp + Cout) = lv;
        }
        if constexpr (EPI == 2) {
#pragma unroll
            for (int r = 0; r < 4; ++r) {
#pragma unroll
                for (int d = 1; d < 16; d <<= 1) {
                    ssum[r] += __shfl_xor(ssum[r], d);
                    ssq[r]  += __shfl_xor(ssq[r], d);
                }
            }
            if (l15 == 0) {
                const int chl = wm * 64 + i * 16 + q * 4;
#pragma unroll
                for (int r = 0; r < 4; ++r) {
                    sstat[(wn * BM + chl + r) * 2]     = ssum[r];
                    sstat[(wn * BM + chl + r) * 2 + 1] = ssq[r];
                }
            }
        }
    }
    if constexpr (EPI == 2) {
        __syncthreads();
        if (tid < BM) {
            float s0 = 0.f, s1 = 0.f;
#pragma unroll
            for (int w = 0; w < CWv; ++w) {
                s0 += sstat[(w * BM + tid) * 2];
                s1 += sstat[(w * BM + tid) * 2 + 1];
            }
            atomicAdd(&stats[(m0 + tid) * 2], s0);
            atomicAdd(&stats[(m0 + tid) * 2 + 1], s1);
        }
    }
}

// ---- final 64->3 conv (BN finalize folded in; BN+ReLU on split input) ------
__global__ __launch_bounds__(256) void finalconv_pm(
    const u16* __restrict__ y3, const float* __restrict__ stats,
    const float* __restrict__ g, const float* __restrict__ be,
    const float* __restrict__ wout, const float* __restrict__ bout,
    float* __restrict__ pts)
{
    __shared__ float swo[3][64];
    __shared__ float ssc[64], ssh[64];
    const int tid = threadIdx.x;
    if (tid < 192) swo[tid / 64][tid % 64] = wout[tid];
    if (tid < 64) {
        const float inv = 1.0f / (float)Nn;
        const float mean = stats[tid * 2] * inv;
        const float var = stats[tid * 2 + 1] * inv - mean * mean;
        const float sc = g[tid] / sqrtf(var + EPSf);
        ssc[tid] = sc;
        ssh[tid] = fmaf(-mean, sc, be[tid]);
    }
    __syncthreads();
    const int n = blockIdx.x * 256 + tid;
    const uint4* yph = (const uint4*)(y3 + (size_t)n * 128);
    float d0 = bout[0], d1 = bout[1], d2 = bout[2];
#pragma unroll
    for (int cc = 0; cc < 8; ++cc) {
        const uint4 H = yph[cc];
        const uint4 L = yph[8 + cc];
        const unsigned hu[4] = {H.x, H.y, H.z, H.w};
        const unsigned lu[4] = {L.x, L.y, L.z, L.w};
#pragma unroll
        for (int e = 0; e < 4; ++e) {
            const int c = cc * 8 + e * 2;
            const float v0 = fjoin((u16)(hu[e] & 0xffff), (u16)(lu[e] & 0xffff));
            const float v1 = fjoin((u16)(hu[e] >> 16), (u16)(lu[e] >> 16));
            const float a0 = fmaxf(fmaf(v0, ssc[c], ssh[c]), 0.f);
            const float a1 = fmaxf(fmaf(v1, ssc[c + 1], ssh[c + 1]), 0.f);
            d0 = fmaf(a0, swo[0][c], d0); d0 = fmaf(a1, swo[0][c + 1], d0);
            d1 = fmaf(a0, swo[1][c], d1); d1 = fmaf(a1, swo[1][c + 1], d1);
            d2 = fmaf(a0, swo[2][c], d2); d2 = fmaf(a1, swo[2][c + 1], d2);
        }
    }
    float4 p = {d0, d1, d2, d0 * d0 + d1 * d1 + d2 * d2};
    *(float4*)(pts + (size_t)n * 4) = p;
}

// ---- graph filtering: 8 threads/point, batch-4 sorting-network insert ------
// Exact top-8 by strict-d comparators (tie order within a thread differs
// from scan-order insert, but exact-key ties are coordinate duplicates --
// validated rounds 0/1: different tie-break rules, identical output).
__global__ __launch_bounds__(512) void knn_kernel(const float* __restrict__ pts,
                                                  float* __restrict__ out) {
    __shared__ __align__(16) float4 sp[Mn];   // 32 KB -> 4 blocks/CU (wave cap)
    const int b = blockIdx.y;
    const int tid = threadIdx.x;
    const float4* pb = (const float4*)pts + (size_t)b * Mn;
    for (int i = tid; i < Mn; i += 512) sp[i] = pb[i];
    __syncthreads();
    const int lane = tid & 63;
    const int wv = tid >> 6;                    // 0..7
    const int seg = lane & 7;                   // segment 0..7
    const int ptl = (wv << 3) | (lane >> 3);    // point-local 0..63
    const int m = blockIdx.x * 64 + ptl;
    const float4 p = sp[m];
    float bd[8]; int bi[8];
#pragma unroll
    for (int k = 0; k < 8; ++k) { bd[k] = 1e30f; bi[k] = 0x7fffffff; }
    const int nb = seg << 8;
    for (int t = 0; t < 256; t += 4) {
        // ---- load 4 candidates, compute keys ----
        float cd[4]; int ci[4];
#pragma unroll
        for (int i = 0; i < 4; ++i) {
            const int n = nb | ((t + seg + i) & 255);   // stagger by seg (bank tiling)
            const float4 q = sp[n];
            const float dot = fmaf(p.x, q.x, fmaf(p.y, q.y, p.z * q.z));
            float d = fmaf(-2.f, dot, q.w);             // key = dist - p.w (monotone)
            d = (n == m) ? 1e30f : d;                   // exclude self
            cd[i] = d; ci[i] = n;
        }
        // ---- sort-4 ascending: (0,1)(2,3)(0,2)(1,3)(1,2) ----
        cswapd(cd[0], ci[0], cd[1], ci[1]);
        cswapd(cd[2], ci[2], cd[3], ci[3]);
        cswapd(cd[0], ci[0], cd[2], ci[2]);
        cswapd(cd[1], ci[1], cd[3], ci[3]);
        cswapd(cd[1], ci[1], cd[2], ci[2]);
        // ---- bitonic lowest-8 of sorted-8 U sorted-4: min phase ----
#pragma unroll
        for (int i = 0; i < 4; ++i) {
            const float db = cd[3 - i]; const int ib = ci[3 - i];
            const bool bl = db < bd[4 + i];
            bd[4 + i] = bl ? db : bd[4 + i];
            bi[4 + i] = bl ? ib : bi[4 + i];
        }
        // ---- bitonic-8 cleaner (restores ascending order) ----
        cswapd(bd[0], bi[0], bd[4], bi[4]);
        cswapd(bd[1], bi[1], bd[5], bi[5]);
        cswapd(bd[2], bi[2], bd[6], bi[6]);
        cswapd(bd[3], bi[3], bd[7], bi[7]);
        cswapd(bd[0], bi[0], bd[2], bi[2]);
        cswapd(bd[1], bi[1], bd[3], bi[3]);
        cswapd(bd[4], bi[4], bd[6], bi[6]);
        cswapd(bd[5], bi[5], bd[7], bi[7]);
        cswapd(bd[0], bi[0], bd[1], bi[1]);
        cswapd(bd[2], bi[2], bd[3], bi[3]);
        cswapd(bd[4], bi[4], bd[5], bi[5]);
        cswapd(bd[6], bi[6], bd[7], bi[7]);
    }
    // 3 shuffle merge rounds: partner = lane ^ r (same point, r in {1,2,4})
#pragma unroll
    for (int r = 1; r <= 4; r <<= 1) {
        float od[8]; int oi[8];
#pragma unroll
        for (int k = 0; k < 8; ++k) {
            od[k] = __shfl_xor(bd[k], r);
            oi[k] = __shfl_xor(bi[k], r);
        }
        float md[8]; int mi[8];
#pragma unroll
        for (int k = 0; k < 8; ++k) {           // lowest-8 of union (bitonic)
            const float da = bd[k], db = od[7 - k];
            const int   ia = bi[k], ib = oi[7 - k];
            const bool bl = (db < da) || (db == da && ib < ia);
            md[k] = bl ? db : da; mi[k] = bl ? ib : ia;
        }
#define CSM(a, c) cswap(md[a], mi[a], md[c], mi[c])
        CSM(0,4); CSM(1,5); CSM(2,6); CSM(3,7);
        CSM(0,2); CSM(1,3); CSM(4,6); CSM(5,7);
        CSM(0,1); CSM(2,3); CSM(4,5); CSM(6,7);
#undef CSM
#pragma unroll
        for (int k = 0; k < 8; ++k) { bd[k] = md[k]; bi[k] = mi[k]; }
    }
    if (seg == 0) {
        float nx = 0.f, ny = 0.f, nz = 0.f;
#pragma unroll
        for (int k = 0; k < 8; ++k) { const float4 q = sp[bi[k]]; nx += q.x; ny += q.y; nz += q.z; }
        const float s8 = 0.125f;
        float* ob = out + (size_t)b * 3 * Mn;
        ob[m]          = 2.f * p.x - nx * s8;
        ob[Mn + m]     = 2.f * p.y - ny * s8;
        ob[2 * Mn + m] = 2.f * p.z - nz * s8;
    }
}

// ============================================================================
extern "C" void kernel_launch(void* const* d_in, const int* in_sizes, int n_in,
                              void* d_out, int out_size, void* d_ws, size_t ws_size,
                              hipStream_t stream)
{
    (void)in_sizes; (void)n_in; (void)out_size;
    const float* z     = (const float*)d_in[0];
    const float* s     = (const float*)d_in[1];
    const float* w_m1  = (const float*)d_in[2];
    const float* b_m1  = (const float*)d_in[3];
    const float* w_m2  = (const float*)d_in[4];
    const float* b_m2  = (const float*)d_in[5];
    const float* w_out = (const float*)d_in[6];
    const float* b_out = (const float*)d_in[7];
    const float* w_c[4]  = {(const float*)d_in[8],  (const float*)d_in[12], (const float*)d_in[16], (const float*)d_in[20]};
    const float* b_c[4]  = {(const float*)d_in[9],  (const float*)d_in[13], (const float*)d_in[17], (const float*)d_in[21]};
    const float* g_c[4]  = {(const float*)d_in[10], (const float*)d_in[14], (const float*)d_in[18], (const float*)d_in[22]};
    const float* be_c[4] = {(const float*)d_in[11], (const float*)d_in[15], (const float*)d_in[19], (const float*)d_in[23]};

    char* ws = (char*)d_ws;
    const size_t MB = 1024ull * 1024ull;
    float* outp = (float*)d_out;
    if (ws_size < 208 * MB) return;   // proven: harness provides >= 208 MiB

    // -------- split-fp16 MFMA path (peak 204 MiB) --------
    u16*   wbuf  = (u16*)ws;
    float* stats = (float*)(ws + 3 * MB);
    u16*   xs  = (u16*)(ws + 4 * MB);
    u16*   x1  = (u16*)(ws + 12 * MB);
    u16*   x2  = (u16*)(ws + 76 * MB);
    u16*   y0  = (u16*)(ws + 12 * MB);   // contiguous after both chunks (RAW)
    u16*   y0a = (u16*)(ws + 12 * MB);   // rows [0, 32K)
    u16*   y0b = (u16*)(ws + 76 * MB);   // rows [32K, 64K)
    u16*   y1  = (u16*)(ws + 140 * MB);  // RAW c1 output
    u16*   y2  = (u16*)(ws + 12 * MB);   // RAW c2 output
    u16*   y3  = (u16*)(ws + 76 * MB);   // RAW c3 output
    float* pts = (float*)(ws + 4 * MB);

    prep_kernel<<<2497, 256, 0, stream>>>(w_m1, w_m2, w_c[0], w_c[1], w_c[2], w_c[3], s, wbuf, xs, stats);
    // m1: [N][32] -> [N][256]  (Ntiles=512, MY=2 -> 1024 blocks)
    mfma_gemm<2, 2, 0, 2, 0, 32><<<1024, 256, 0, stream>>>(wbuf, xs, x1, b_m1, nullptr, nullptr, nullptr, nullptr, nullptr, 256);
    // m2: [N][256] -> [N][512] (Ntiles=512, MY=4 -> 2048 blocks)
    mfma_gemm<2, 2, 1, 4, 0, 256><<<2048, 256, 0, stream>>>(wbuf + 16384, x1, x2, b_m2, z, nullptr, nullptr, nullptr, nullptr, 512);
    // c0 a/b: rows halves      (Ntiles=256, MY=4 -> 1024 blocks each) -> RAW y0 + stats
    mfma_gemm<2, 2, 2, 4, 0, 512><<<1024, 256, 0, stream>>>(wbuf + 278528, x2, y0a, b_c[0], nullptr, nullptr, nullptr, nullptr, stats + 0, 512);
    mfma_gemm<2, 2, 2, 4, 0, 512><<<1024, 256, 0, stream>>>(wbuf + 278528, x2 + (size_t)Hn * 1024, y0b, b_c[0], nullptr, nullptr, nullptr, nullptr, stats + 0, 512);
    // c1: BN0+ReLU fused on B-input (finalize folded: stats+0, g0, be0); RAW y1 + stats
    mfma_gemm<2, 2, 2, 2, 1, 512><<<1024, 256, 0, stream>>>(wbuf + 802816, y0, y1, b_c[1], nullptr, stats + 0, g_c[0], be_c[0], stats + 1024, 256);
    // c2: BN1+ReLU fused on B-input (stats+1024, g1, be1); RAW y2 + stats
    mfma_gemm<2, 2, 2, 1, 1, 256><<<512, 256, 0, stream>>>(wbuf + 1064960, y1, y2, b_c[2], nullptr, stats + 1024, g_c[1], be_c[1], stats + 2048, 128);
    // c3: BN2+ReLU fused on B-input (stats+2048, g2, be2); RAW y3 + stats
    mfma_gemm<1, 4, 2, 1, 1, 128><<<256, 256, 0, stream>>>(wbuf + 1130496, y2, y3, b_c[3], nullptr, stats + 2048, g_c[2], be_c[2], stats + 3072, 64);
    // final conv: BN3 finalize folded (stats+3072, g3, be3)
    finalconv_pm<<<Nn / 256, 256, 0, stream>>>(y3, stats + 3072, g_c[3], be_c[3], w_out, b_out, pts);
    knn_kernel<<<dim3(Mn / 64, Bn), 512, 0, stream>>>(pts, outp);
}